// Round 1
// baseline (1929.604 us; speedup 1.0000x reference)
//
#include <hip/hip_runtime.h>
#include <hip/hip_bf16.h>
#include <cstdio>

// ---------------------------------------------------------------------------
// Decoder layer: B=8, L=1024, D=512, H=8, depth=64, FFN=2048, MAX_REL=256
// Outputs (fp32, concat): out[8,1024,512], attn_w[8,8,1024,1024], ca_w[same]
// ---------------------------------------------------------------------------

static __device__ __forceinline__ float4 ld4(const float* p) {
    return *reinterpret_cast<const float4*>(p);
}
static __device__ __forceinline__ void st4(float* p, const float4& v) {
    *reinterpret_cast<float4*>(p) = v;
}

static __device__ __forceinline__ void fma44(float acc[4][4], const float4& a, const float4& b) {
    float ai[4] = {a.x, a.y, a.z, a.w};
    float bj[4] = {b.x, b.y, b.z, b.w};
#pragma unroll
    for (int i = 0; i < 4; ++i)
#pragma unroll
        for (int j = 0; j < 4; ++j)
            acc[i][j] = fmaf(ai[i], bj[j], acc[i][j]);
}

// ---------------------------------------------------------------------------
// Generic fp32 GEMM: C[M,N] = A[M,K] @ W[K,N] + bias (+optional relu)
// BM=BN=64, BK=16, 256 threads, 4x4 microtile.
// Requires M%64==0, N%64==0, K%16==0.
// ---------------------------------------------------------------------------
__global__ __launch_bounds__(256) void gemm64(
    const float* __restrict__ A, const float* __restrict__ W,
    const float* __restrict__ bias, float* __restrict__ C,
    int M, int N, int K, int relu)
{
    __shared__ float As[16][68];   // [k][m] transposed
    __shared__ float Bs[16][68];   // [k][n]
    const int t  = threadIdx.x;
    const int tx = t & 15, ty = t >> 4;
    const int m0 = blockIdx.y * 64, n0 = blockIdx.x * 64;
    const int ar = t >> 2, ac = (t & 3) * 4;     // A tile: 64 rows x 16 k
    const int wr = t >> 4, wc = (t & 15) * 4;    // W tile: 16 k x 64 n
    float acc[4][4] = {};
    for (int k0 = 0; k0 < K; k0 += 16) {
        float4 av = ld4(&A[(size_t)(m0 + ar) * K + (k0 + ac)]);
        float4 wv = ld4(&W[(size_t)(k0 + wr) * N + (n0 + wc)]);
        __syncthreads();
        As[ac + 0][ar] = av.x; As[ac + 1][ar] = av.y;
        As[ac + 2][ar] = av.z; As[ac + 3][ar] = av.w;
        st4(&Bs[wr][wc], wv);
        __syncthreads();
#pragma unroll
        for (int kk = 0; kk < 16; ++kk) {
            float4 a = ld4(&As[kk][ty * 4]);
            float4 b = ld4(&Bs[kk][tx * 4]);
            fma44(acc, a, b);
        }
    }
    float4 bv = ld4(&bias[n0 + tx * 4]);
    float bj[4] = {bv.x, bv.y, bv.z, bv.w};
#pragma unroll
    for (int i = 0; i < 4; ++i) {
        float4 o;
        o.x = acc[i][0] + bj[0]; o.y = acc[i][1] + bj[1];
        o.z = acc[i][2] + bj[2]; o.w = acc[i][3] + bj[3];
        if (relu) {
            o.x = fmaxf(o.x, 0.f); o.y = fmaxf(o.y, 0.f);
            o.z = fmaxf(o.z, 0.f); o.w = fmaxf(o.w, 0.f);
        }
        st4(&C[(size_t)(m0 + ty * 4 + i) * N + (n0 + tx * 4)], o);
    }
}

// ---------------------------------------------------------------------------
// rel_q[flat=(b*8+h)*1024+l][r] = sum_d Q[(b*1024+l)*512 + h*64 + d] * R[r*64+d]
// Output bf16, row stride 513. Grid: (9 col-tiles, 1024 row-tiles), 256 thr.
// ---------------------------------------------------------------------------
__global__ __launch_bounds__(256) void relq64(
    const float* __restrict__ Q, const float* __restrict__ R,
    __hip_bfloat16* __restrict__ out)
{
    __shared__ float Qt[64][68];   // [d][row]
    __shared__ float Rt[64][68];   // [d][col]
    const int t = threadIdx.x, tx = t & 15, ty = t >> 4;
    const int r0 = blockIdx.y * 64, c0 = blockIdx.x * 64;
    const int d4 = (t & 15) * 4;
#pragma unroll
    for (int rr = 0; rr < 4; ++rr) {
        int r = (t >> 4) + rr * 16;
        int flat = r0 + r;
        int b = flat >> 13, h = (flat >> 10) & 7, l = flat & 1023;
        float4 qv = ld4(&Q[((size_t)b * 1024 + l) * 512 + h * 64 + d4]);
        Qt[d4 + 0][r] = qv.x; Qt[d4 + 1][r] = qv.y;
        Qt[d4 + 2][r] = qv.z; Qt[d4 + 3][r] = qv.w;
        int c = c0 + r;
        float4 rv = make_float4(0.f, 0.f, 0.f, 0.f);
        if (c < 513) rv = ld4(&R[(size_t)c * 64 + d4]);
        Rt[d4 + 0][r] = rv.x; Rt[d4 + 1][r] = rv.y;
        Rt[d4 + 2][r] = rv.z; Rt[d4 + 3][r] = rv.w;
    }
    __syncthreads();
    float acc[4][4] = {};
#pragma unroll 16
    for (int dd = 0; dd < 64; ++dd) {
        float4 a = ld4(&Qt[dd][ty * 4]);
        float4 b = ld4(&Rt[dd][tx * 4]);
        fma44(acc, a, b);
    }
#pragma unroll
    for (int i = 0; i < 4; ++i) {
        int row = r0 + ty * 4 + i;
#pragma unroll
        for (int j = 0; j < 4; ++j) {
            int col = c0 + tx * 4 + j;
            if (col < 513) out[(size_t)row * 513 + col] = __float2bfloat16(acc[i][j]);
        }
    }
}

// ---------------------------------------------------------------------------
// Scores: S[bh,q,k] = (q.k + rel_q[bh,q,clip(k-q)+256]) * 0.125 + mask*(-1e9)
// Grid: (16 k-tiles, 16 q-tiles, 64 bh). 256 threads, 4x4 microtile.
// ---------------------------------------------------------------------------
__global__ __launch_bounds__(256) void scores64(
    const float* __restrict__ Q, const float* __restrict__ Kmat,
    const __hip_bfloat16* __restrict__ relq, const float* __restrict__ mask,
    float* __restrict__ S)
{
    __shared__ float Qt[64][68];   // [d][q-row]
    __shared__ float Kt[64][68];   // [d][k-row]
    const int t = threadIdx.x, tx = t & 15, ty = t >> 4;
    const int bh = blockIdx.z, b = bh >> 3, h = bh & 7;
    const int q0 = blockIdx.y * 64, k0 = blockIdx.x * 64;
    const int d4 = (t & 15) * 4;
#pragma unroll
    for (int rr = 0; rr < 4; ++rr) {
        int r = (t >> 4) + rr * 16;
        float4 qv = ld4(&Q[((size_t)b * 1024 + (q0 + r)) * 512 + h * 64 + d4]);
        float4 kv = ld4(&Kmat[((size_t)b * 1024 + (k0 + r)) * 512 + h * 64 + d4]);
        Qt[d4 + 0][r] = qv.x; Qt[d4 + 1][r] = qv.y;
        Qt[d4 + 2][r] = qv.z; Qt[d4 + 3][r] = qv.w;
        Kt[d4 + 0][r] = kv.x; Kt[d4 + 1][r] = kv.y;
        Kt[d4 + 2][r] = kv.z; Kt[d4 + 3][r] = kv.w;
    }
    __syncthreads();
    float acc[4][4] = {};
#pragma unroll 16
    for (int dd = 0; dd < 64; ++dd) {
        float4 a = ld4(&Qt[dd][ty * 4]);
        float4 b = ld4(&Kt[dd][tx * 4]);
        fma44(acc, a, b);
    }
#pragma unroll
    for (int i = 0; i < 4; ++i) {
        int q = q0 + ty * 4 + i;
        const float* mrow = &mask[((size_t)b * 1024 + q) * 1024 + k0];
        const __hip_bfloat16* rrow = &relq[((size_t)bh * 1024 + q) * 513];
        float vals[4];
#pragma unroll
        for (int j = 0; j < 4; ++j) {
            int k = k0 + tx * 4 + j;
            int d = k - q;
            d = d < -256 ? -256 : (d > 256 ? 256 : d);
            float rel = __bfloat162float(rrow[d + 256]);
            vals[j] = (acc[i][j] + rel) * 0.125f + mrow[tx * 4 + j] * (-1e9f);
        }
        float4 o = make_float4(vals[0], vals[1], vals[2], vals[3]);
        st4(&S[((size_t)bh * 1024 + q) * 1024 + (k0 + tx * 4)], o);
    }
}

// ---------------------------------------------------------------------------
// Row softmax over 1024 elems, in place. One block (256 thr) per row.
// ---------------------------------------------------------------------------
__global__ __launch_bounds__(256) void softmax1024(float* __restrict__ S)
{
    float* p = S + (size_t)blockIdx.x * 1024;
    const int t = threadIdx.x;
    float4 x = ld4(&p[t * 4]);
    float m = fmaxf(fmaxf(x.x, x.y), fmaxf(x.z, x.w));
#pragma unroll
    for (int o = 32; o > 0; o >>= 1) m = fmaxf(m, __shfl_xor(m, o));
    __shared__ float rmax[4], rsum[4];
    if ((t & 63) == 0) rmax[t >> 6] = m;
    __syncthreads();
    m = fmaxf(fmaxf(rmax[0], rmax[1]), fmaxf(rmax[2], rmax[3]));
    float4 e;
    e.x = expf(x.x - m); e.y = expf(x.y - m);
    e.z = expf(x.z - m); e.w = expf(x.w - m);
    float s = e.x + e.y + e.z + e.w;
#pragma unroll
    for (int o = 32; o > 0; o >>= 1) s += __shfl_xor(s, o);
    if ((t & 63) == 0) rsum[t >> 6] = s;
    __syncthreads();
    s = rsum[0] + rsum[1] + rsum[2] + rsum[3];
    float inv = 1.0f / s;
    e.x *= inv; e.y *= inv; e.z *= inv; e.w *= inv;
    st4(&p[t * 4], e);
}

// ---------------------------------------------------------------------------
// PV: H[(b*1024+q)*512 + h*64 + d] = sum_k W[bh,q,k] * V[(b*1024+k)*512+h*64+d]
// Grid: (16 q-tiles, 64 bh). 256 threads, 4x4 microtile, BK=32.
// ---------------------------------------------------------------------------
__global__ __launch_bounds__(256) void pv64(
    const float* __restrict__ Wgt, const float* __restrict__ V,
    float* __restrict__ H)
{
    __shared__ float Wt[32][68];   // [k][q-row]
    __shared__ float Vs[32][68];   // [k][d]
    const int t = threadIdx.x, tx = t & 15, ty = t >> 4;
    const int bh = blockIdx.y, b = bh >> 3, h = bh & 7;
    const int q0 = blockIdx.x * 64;
    const int wr0 = t >> 3, wc = (t & 7) * 4;
    const int vr0 = t >> 4, vc = (t & 15) * 4;
    float acc[4][4] = {};
    for (int kc = 0; kc < 1024; kc += 32) {
        float4 wv0 = ld4(&Wgt[((size_t)bh * 1024 + q0 + wr0)      * 1024 + kc + wc]);
        float4 wv1 = ld4(&Wgt[((size_t)bh * 1024 + q0 + wr0 + 32) * 1024 + kc + wc]);
        float4 vv0 = ld4(&V[((size_t)b * 1024 + kc + vr0)      * 512 + h * 64 + vc]);
        float4 vv1 = ld4(&V[((size_t)b * 1024 + kc + vr0 + 16) * 512 + h * 64 + vc]);
        __syncthreads();
        Wt[wc + 0][wr0] = wv0.x; Wt[wc + 1][wr0] = wv0.y;
        Wt[wc + 2][wr0] = wv0.z; Wt[wc + 3][wr0] = wv0.w;
        Wt[wc + 0][wr0 + 32] = wv1.x; Wt[wc + 1][wr0 + 32] = wv1.y;
        Wt[wc + 2][wr0 + 32] = wv1.z; Wt[wc + 3][wr0 + 32] = wv1.w;
        st4(&Vs[vr0][vc], vv0);
        st4(&Vs[vr0 + 16][vc], vv1);
        __syncthreads();
#pragma unroll
        for (int kk = 0; kk < 32; ++kk) {
            float4 a = ld4(&Wt[kk][ty * 4]);
            float4 b = ld4(&Vs[kk][tx * 4]);
            fma44(acc, a, b);
        }
    }
#pragma unroll
    for (int i = 0; i < 4; ++i) {
        float4 o = make_float4(acc[i][0], acc[i][1], acc[i][2], acc[i][3]);
        st4(&H[((size_t)b * 1024 + q0 + ty * 4 + i) * 512 + h * 64 + tx * 4], o);
    }
}

// ---------------------------------------------------------------------------
// LayerNorm over 512: out = LN(Xp + Res) * g + be. One block (128 thr) / row.
// ---------------------------------------------------------------------------
__global__ __launch_bounds__(128) void ln512(
    const float* __restrict__ Xp, const float* __restrict__ Res,
    const float* __restrict__ g, const float* __restrict__ be,
    float* __restrict__ out)
{
    const size_t row = blockIdx.x;
    const int t = threadIdx.x;
    float4 x = ld4(&Xp[row * 512 + t * 4]);
    float4 r = ld4(&Res[row * 512 + t * 4]);
    x.x += r.x; x.y += r.y; x.z += r.z; x.w += r.w;
    float s  = x.x + x.y + x.z + x.w;
    float ss = x.x * x.x + x.y * x.y + x.z * x.z + x.w * x.w;
#pragma unroll
    for (int o = 32; o > 0; o >>= 1) {
        s  += __shfl_xor(s, o);
        ss += __shfl_xor(ss, o);
    }
    __shared__ float sm[2], sq[2];
    if ((t & 63) == 0) { sm[t >> 6] = s; sq[t >> 6] = ss; }
    __syncthreads();
    s = sm[0] + sm[1]; ss = sq[0] + sq[1];
    const float mean = s * (1.f / 512.f);
    const float var  = ss * (1.f / 512.f) - mean * mean;
    const float rstd = rsqrtf(var + 1e-3f);
    float4 gv = ld4(&g[t * 4]), bv = ld4(&be[t * 4]);
    float4 o;
    o.x = (x.x - mean) * rstd * gv.x + bv.x;
    o.y = (x.y - mean) * rstd * gv.y + bv.y;
    o.z = (x.z - mean) * rstd * gv.z + bv.z;
    o.w = (x.w - mean) * rstd * gv.w + bv.w;
    st4(&out[row * 512 + t * 4], o);
}

// ---------------------------------------------------------------------------

extern "C" void kernel_launch(void* const* d_in, const int* in_sizes, int n_in,
                              void* d_out, int out_size, void* d_ws, size_t ws_size,
                              hipStream_t stream)
{
    (void)in_sizes; (void)n_in; (void)out_size;
    const float* inputs    = (const float*)d_in[0];
    const float* enc_kv    = (const float*)d_in[1];
    const float* pad_mask  = (const float*)d_in[2];
    const float* look_mask = (const float*)d_in[3];
    // d_in[4] = training scalar (ignored; inference path)
    const float* saWq  = (const float*)d_in[5];
    const float* sabq  = (const float*)d_in[6];
    const float* saWk  = (const float*)d_in[7];
    const float* sabk  = (const float*)d_in[8];
    const float* saWv  = (const float*)d_in[9];
    const float* sabv  = (const float*)d_in[10];
    const float* saWo  = (const float*)d_in[11];
    const float* sabo  = (const float*)d_in[12];
    const float* sarel = (const float*)d_in[13];
    const float* salg  = (const float*)d_in[14];
    const float* salb  = (const float*)d_in[15];
    const float* caWq  = (const float*)d_in[16];
    const float* cabq  = (const float*)d_in[17];
    const float* caWk  = (const float*)d_in[18];
    const float* cabk  = (const float*)d_in[19];
    const float* caWv  = (const float*)d_in[20];
    const float* cabv  = (const float*)d_in[21];
    const float* caWo  = (const float*)d_in[22];
    const float* cabo  = (const float*)d_in[23];
    const float* carel = (const float*)d_in[24];
    const float* calg  = (const float*)d_in[25];
    const float* calb  = (const float*)d_in[26];
    const float* fW1   = (const float*)d_in[27];
    const float* fb1   = (const float*)d_in[28];
    const float* fW2   = (const float*)d_in[29];
    const float* fb2   = (const float*)d_in[30];
    const float* flg   = (const float*)d_in[31];
    const float* flb   = (const float*)d_in[32];

    float* out    = (float*)d_out;
    float* attn_w = out + (size_t)8 * 1024 * 512;            // 4,194,304
    float* ca_w   = attn_w + (size_t)8 * 8 * 1024 * 1024;    // +67,108,864

    char* ws = (char*)d_ws;
    const size_t SZ_MAT = (size_t)8192 * 512 * 4;            // 16 MiB
    const size_t SZ_REL = (size_t)65536 * 513 * 2;           // 64.1 MiB (bf16)
    const size_t need = 7 * SZ_MAT + SZ_REL;                 // ~184.7 MB
    if (ws_size < need) {
        fprintf(stderr, "kernel_launch: ws too small (%zu < %zu)\n", ws_size, need);
        return;
    }
    float* Qb    = (float*)(ws + 0 * SZ_MAT);
    float* Kb    = (float*)(ws + 1 * SZ_MAT);
    float* Vb    = (float*)(ws + 2 * SZ_MAT);
    float* heads = (float*)(ws + 3 * SZ_MAT);
    float* x1    = (float*)(ws + 4 * SZ_MAT);
    float* x2    = (float*)(ws + 5 * SZ_MAT);
    float* Pb    = (float*)(ws + 6 * SZ_MAT);
    __hip_bfloat16* relq = (__hip_bfloat16*)(ws + 7 * SZ_MAT);
    float* hidden = (float*)(ws + 7 * SZ_MAT);  // aliases relq: disjoint lifetime

    const dim3 T256(256), T128(128);
    const dim3 Gproj(8, 128);        // N=512, M=8192
    const dim3 Grel(9, 1024);
    const dim3 Gsc(16, 16, 64);
    const dim3 Gsm(65536);
    const dim3 Gpv(16, 64);
    const dim3 Gln(8192);

    // ---------------- self attention ----------------
    gemm64<<<Gproj, T256, 0, stream>>>(inputs, saWq, sabq, Qb, 8192, 512, 512, 0);
    gemm64<<<Gproj, T256, 0, stream>>>(inputs, saWk, sabk, Kb, 8192, 512, 512, 0);
    gemm64<<<Gproj, T256, 0, stream>>>(inputs, saWv, sabv, Vb, 8192, 512, 512, 0);
    relq64<<<Grel, T256, 0, stream>>>(Qb, sarel, relq);
    scores64<<<Gsc, T256, 0, stream>>>(Qb, Kb, relq, look_mask, attn_w);
    softmax1024<<<Gsm, T256, 0, stream>>>(attn_w);
    pv64<<<Gpv, T256, 0, stream>>>(attn_w, Vb, heads);
    gemm64<<<Gproj, T256, 0, stream>>>(heads, saWo, sabo, Pb, 8192, 512, 512, 0);
    ln512<<<Gln, T128, 0, stream>>>(Pb, inputs, salg, salb, x1);

    // ---------------- cross attention ----------------
    gemm64<<<Gproj, T256, 0, stream>>>(x1, caWq, cabq, Qb, 8192, 512, 512, 0);
    gemm64<<<Gproj, T256, 0, stream>>>(enc_kv, caWk, cabk, Kb, 8192, 512, 512, 0);
    gemm64<<<Gproj, T256, 0, stream>>>(enc_kv, caWv, cabv, Vb, 8192, 512, 512, 0);
    relq64<<<Grel, T256, 0, stream>>>(Qb, carel, relq);
    scores64<<<Gsc, T256, 0, stream>>>(Qb, Kb, relq, pad_mask, ca_w);
    softmax1024<<<Gsm, T256, 0, stream>>>(ca_w);
    pv64<<<Gpv, T256, 0, stream>>>(ca_w, Vb, heads);
    gemm64<<<Gproj, T256, 0, stream>>>(heads, caWo, cabo, Pb, 8192, 512, 512, 0);
    ln512<<<Gln, T128, 0, stream>>>(Pb, x1, calg, calb, x2);

    // ---------------- FFN ----------------
    gemm64<<<dim3(32, 128), T256, 0, stream>>>(x2, fW1, fb1, hidden, 8192, 2048, 512, 1);
    gemm64<<<Gproj, T256, 0, stream>>>(hidden, fW2, fb2, Pb, 8192, 512, 2048, 0);
    ln512<<<Gln, T128, 0, stream>>>(Pb, x2, flg, flb, out);
}

// Round 2
// 990.397 us; speedup vs baseline: 1.9483x; 1.9483x over previous
//
#include <hip/hip_runtime.h>
#include <hip/hip_bf16.h>
#include <cstdio>

// ---------------------------------------------------------------------------
// Decoder layer: B=8, L=1024, D=512, H=8, depth=64, FFN=2048, MAX_REL=256
// Outputs (fp32, concat): out[8,1024,512], attn_w[8,8,1024,1024], ca_w[same]
// Round 1: all matmul-shaped work on bf16 MFMA (16x16x32), fp32 softmax/LN.
// ---------------------------------------------------------------------------

typedef __attribute__((ext_vector_type(8))) short short8v;   // 8 bf16 (4 VGPR)
typedef __attribute__((ext_vector_type(4))) short short4v;   // 4 bf16 (8 B)
typedef __attribute__((ext_vector_type(4))) float f32x4;

static __device__ __forceinline__ unsigned short f2bf(float f) {
    unsigned int u = __float_as_uint(f);
    unsigned int r = (u + 0x7fffu + ((u >> 16) & 1u)) >> 16;
    return (unsigned short)r;
}
static __device__ __forceinline__ float bf2f(unsigned short s) {
    return __uint_as_float(((unsigned int)s) << 16);
}

static __device__ __forceinline__ f32x4 mfma_bf16(short8v a, short8v b, f32x4 c) {
    return __builtin_amdgcn_mfma_f32_16x16x32_bf16(a, b, c, 0, 0, 0);
}

// async global->LDS, 16B per lane. LDS dest: wave-uniform base + lane*16.
static __device__ __forceinline__ void async16(const void* g, void* l) {
    __builtin_amdgcn_global_load_lds(
        (const __attribute__((address_space(1))) unsigned int*)g,
        (__attribute__((address_space(3))) unsigned int*)l,
        16, 0, 0);
}

// Fragment conventions for mfma_f32_16x16x32_bf16 (per guide §3):
//   A-frag: lane holds A[row = lane&15][k = (lane>>4)*8 + j], j=0..7
//   B-frag: lane holds B[k = (lane>>4)*8 + j][col = lane&15]  (read from B^T rows)
//   C/D   : col = lane&15, row = (lane>>4)*4 + reg
// LDS tiles are [rows][32 k] bf16 (64 B rows) -> frag read = ds_read_b128 at
// row*64 + (lane>>4)*16 bytes; rows stride 16 dwords -> bank-floor-optimal.

// ---------------------------------------------------------------------------
// Generic bf16 MFMA GEMM: C[M,N] = A[M,K] @ BT[N,K]^T + bias
// Tile 128x128, BK=32, 256 threads (4 waves, 2x2), global_load_lds staging.
// M%128==0, N%128==0, K%32==0.
// ---------------------------------------------------------------------------
__global__ __launch_bounds__(256) void gemm_bf16(
    const unsigned short* __restrict__ A, const unsigned short* __restrict__ BT,
    const float* __restrict__ bias, float* __restrict__ Cf,
    unsigned short* __restrict__ Cb, int M, int N, int K, int relu)
{
    __shared__ __attribute__((aligned(16))) unsigned short As[128 * 32];
    __shared__ __attribute__((aligned(16))) unsigned short Bs[128 * 32];
    const int t = threadIdx.x, lane = t & 63, w = t >> 6;
    const int wm = w >> 1, wn = w & 1;
    const int m0 = blockIdx.y * 128, n0 = blockIdx.x * 128;
    f32x4 acc[4][4];
#pragma unroll
    for (int m = 0; m < 4; ++m)
#pragma unroll
        for (int n = 0; n < 4; ++n) acc[m][n] = (f32x4){0.f, 0.f, 0.f, 0.f};

    const int srow = lane >> 2, sg = lane & 3;   // staging: 16 rows x 4 granules
    for (int k0 = 0; k0 < K; k0 += 32) {
#pragma unroll
        for (int c = w; c < 8; c += 4) {         // 2 A-calls + 2 B-calls per wave
            async16(A  + (size_t)(m0 + c * 16 + srow) * K + k0 + sg * 8, &As[c * 512]);
            async16(BT + (size_t)(n0 + c * 16 + srow) * K + k0 + sg * 8, &Bs[c * 512]);
        }
        __syncthreads();
        short8v a[4], b[4];
#pragma unroll
        for (int m = 0; m < 4; ++m)
            a[m] = *(const short8v*)&As[(wm * 64 + m * 16 + (lane & 15)) * 32 + (lane >> 4) * 8];
#pragma unroll
        for (int n = 0; n < 4; ++n)
            b[n] = *(const short8v*)&Bs[(wn * 64 + n * 16 + (lane & 15)) * 32 + (lane >> 4) * 8];
#pragma unroll
        for (int m = 0; m < 4; ++m)
#pragma unroll
            for (int n = 0; n < 4; ++n)
                acc[m][n] = mfma_bf16(a[m], b[n], acc[m][n]);
        __syncthreads();
    }
#pragma unroll
    for (int m = 0; m < 4; ++m) {
        int gm = m0 + wm * 64 + m * 16 + (lane >> 4) * 4;
#pragma unroll
        for (int n = 0; n < 4; ++n) {
            int gn = n0 + wn * 64 + n * 16 + (lane & 15);
            float bv = bias ? bias[gn] : 0.f;
#pragma unroll
            for (int j = 0; j < 4; ++j) {
                float v = acc[m][n][j] + bv;
                if (relu) v = fmaxf(v, 0.f);
                size_t off = (size_t)(gm + j) * N + gn;
                if (Cf) Cf[off] = v;
                if (Cb) Cb[off] = f2bf(v);
            }
        }
    }
}

// ---------------------------------------------------------------------------
// Scores: S[bh,q,k] = (Q.K + rel)(1/8) + mask*(-1e9). 128x128 tile, K=64.
// Grid (8 k-tiles, 8 q-tiles, 64 bh).
// ---------------------------------------------------------------------------
__global__ __launch_bounds__(256) void scores_mfma(
    const unsigned short* __restrict__ Q, const unsigned short* __restrict__ Kb,
    const unsigned short* __restrict__ relq, const float* __restrict__ mask,
    float* __restrict__ S)
{
    __shared__ __attribute__((aligned(16))) unsigned short As[2 * 128 * 32];
    __shared__ __attribute__((aligned(16))) unsigned short Bs[2 * 128 * 32];
    const int t = threadIdx.x, lane = t & 63, w = t >> 6;
    const int wm = w >> 1, wn = w & 1;
    const int bh = blockIdx.z, b = bh >> 3, h = bh & 7;
    const int q0 = blockIdx.y * 128, k0 = blockIdx.x * 128;
    const int srow = lane >> 2, sg = lane & 3;
#pragma unroll
    for (int c = w; c < 16; c += 4) {      // kg = c>>3, 16-row group rg = c&7
        int kg = c >> 3, rg = c & 7;
        int r = rg * 16 + srow;
        async16(Q  + ((size_t)(b * 1024 + q0 + r)) * 512 + h * 64 + kg * 32 + sg * 8,
                &As[kg * 4096 + rg * 512]);
        async16(Kb + ((size_t)(b * 1024 + k0 + r)) * 512 + h * 64 + kg * 32 + sg * 8,
                &Bs[kg * 4096 + rg * 512]);
    }
    __syncthreads();
    f32x4 acc[4][4];
#pragma unroll
    for (int m = 0; m < 4; ++m)
#pragma unroll
        for (int n = 0; n < 4; ++n) acc[m][n] = (f32x4){0.f, 0.f, 0.f, 0.f};
#pragma unroll
    for (int kg = 0; kg < 2; ++kg) {
        short8v a[4], bb[4];
#pragma unroll
        for (int m = 0; m < 4; ++m)
            a[m] = *(const short8v*)&As[kg * 4096 + (wm * 64 + m * 16 + (lane & 15)) * 32 + (lane >> 4) * 8];
#pragma unroll
        for (int n = 0; n < 4; ++n)
            bb[n] = *(const short8v*)&Bs[kg * 4096 + (wn * 64 + n * 16 + (lane & 15)) * 32 + (lane >> 4) * 8];
#pragma unroll
        for (int m = 0; m < 4; ++m)
#pragma unroll
            for (int n = 0; n < 4; ++n)
                acc[m][n] = mfma_bf16(a[m], bb[n], acc[m][n]);
    }
#pragma unroll
    for (int m = 0; m < 4; ++m) {
        int qr = q0 + wm * 64 + m * 16 + (lane >> 4) * 4;
#pragma unroll
        for (int j = 0; j < 4; ++j) {
            int q = qr + j;
            const unsigned short* rrow = relq + ((size_t)bh * 1024 + q) * 513;
            const float* mrow = mask + ((size_t)b * 1024 + q) * 1024;
            float* srow_p = S + ((size_t)bh * 1024 + q) * 1024;
#pragma unroll
            for (int n = 0; n < 4; ++n) {
                int k = k0 + wn * 64 + n * 16 + (lane & 15);
                int d = k - q;
                d = d < -256 ? -256 : (d > 256 ? 256 : d);
                float rel = bf2f(rrow[d + 256]);
                srow_p[k] = (acc[m][n][j] + rel) * 0.125f + mrow[k] * (-1e9f);
            }
        }
    }
}

// ---------------------------------------------------------------------------
// relq[flat=(b*8+h)*1024+l][r] = Q[b,l,h*64+:64] . rel_emb[r]. bf16 out, 513 cols.
// Grid (5 n-tiles(128), 512 m-tiles(128)).
// ---------------------------------------------------------------------------
__global__ __launch_bounds__(256) void relq_mfma(
    const unsigned short* __restrict__ Q, const unsigned short* __restrict__ R,
    unsigned short* __restrict__ out)
{
    __shared__ __attribute__((aligned(16))) unsigned short As[2 * 128 * 32];
    __shared__ __attribute__((aligned(16))) unsigned short Bs[2 * 128 * 32];
    const int t = threadIdx.x, lane = t & 63, w = t >> 6;
    const int wm = w >> 1, wn = w & 1;
    const int r0 = blockIdx.y * 128, n0 = blockIdx.x * 128;
    const int srow = lane >> 2, sg = lane & 3;
#pragma unroll
    for (int c = w; c < 16; c += 4) {
        int kg = c >> 3, rg = c & 7;
        int rr = rg * 16 + srow;
        int flat = r0 + rr;
        int b = flat >> 13, h = (flat >> 10) & 7, l = flat & 1023;
        async16(Q + ((size_t)(b * 1024 + l)) * 512 + h * 64 + kg * 32 + sg * 8,
                &As[kg * 4096 + rg * 512]);
        int nn = n0 + rr; if (nn > 512) nn = 512;
        async16(R + (size_t)nn * 64 + kg * 32 + sg * 8, &Bs[kg * 4096 + rg * 512]);
    }
    __syncthreads();
    f32x4 acc[4][4];
#pragma unroll
    for (int m = 0; m < 4; ++m)
#pragma unroll
        for (int n = 0; n < 4; ++n) acc[m][n] = (f32x4){0.f, 0.f, 0.f, 0.f};
#pragma unroll
    for (int kg = 0; kg < 2; ++kg) {
        short8v a[4], bb[4];
#pragma unroll
        for (int m = 0; m < 4; ++m)
            a[m] = *(const short8v*)&As[kg * 4096 + (wm * 64 + m * 16 + (lane & 15)) * 32 + (lane >> 4) * 8];
#pragma unroll
        for (int n = 0; n < 4; ++n)
            bb[n] = *(const short8v*)&Bs[kg * 4096 + (wn * 64 + n * 16 + (lane & 15)) * 32 + (lane >> 4) * 8];
#pragma unroll
        for (int m = 0; m < 4; ++m)
#pragma unroll
            for (int n = 0; n < 4; ++n)
                acc[m][n] = mfma_bf16(a[m], bb[n], acc[m][n]);
    }
#pragma unroll
    for (int m = 0; m < 4; ++m) {
        int row = r0 + wm * 64 + m * 16 + (lane >> 4) * 4;
#pragma unroll
        for (int n = 0; n < 4; ++n) {
            int col = n0 + wn * 64 + n * 16 + (lane & 15);
            if (col < 513) {
#pragma unroll
                for (int j = 0; j < 4; ++j)
                    out[(size_t)(row + j) * 513 + col] = f2bf(acc[m][n][j]);
            }
        }
    }
}

// ---------------------------------------------------------------------------
// V transpose per head: Vb[b,k,h*64+d] (bf16) -> Vt[bh,d,k] (bf16 [64][1024])
// Grid (8 k-tiles(128), 64 bh).
// ---------------------------------------------------------------------------
__global__ __launch_bounds__(256) void transpose_v(
    const unsigned short* __restrict__ Vb, unsigned short* __restrict__ Vt)
{
    __shared__ unsigned short T[128][72];
    const int bh = blockIdx.y, b = bh >> 3, h = bh & 7;
    const int k0 = blockIdx.x * 128;
    const int t = threadIdx.x;
    {
        int r = t >> 1, half = t & 1;
        const unsigned short* gp = Vb + ((size_t)(b * 1024 + k0 + r)) * 512 + h * 64 + half * 32;
#pragma unroll
        for (int i = 0; i < 8; ++i)
            *(short4v*)&T[r][half * 32 + i * 4] = *(const short4v*)(gp + i * 4);
    }
    __syncthreads();
    {
        int d = t >> 2, qtr = t & 3;
        unsigned short* gp = Vt + ((size_t)bh * 64 + d) * 1024 + k0 + qtr * 32;
#pragma unroll
        for (int i = 0; i < 32; i += 4) {
            short4v v;
            v.x = T[qtr * 32 + i + 0][d];
            v.y = T[qtr * 32 + i + 1][d];
            v.z = T[qtr * 32 + i + 2][d];
            v.w = T[qtr * 32 + i + 3][d];
            *(short4v*)(gp + i) = v;
        }
    }
}

// ---------------------------------------------------------------------------
// PV: heads[b,q,h*64+d] = sum_k P[bh,q,k] * V[b,k,h*64+d]; P fp32 -> bf16 in
// staging. Tile 128q x 64d, BK=32, 4 waves split along q. Grid (8, 64 bh).
// ---------------------------------------------------------------------------
__global__ __launch_bounds__(256) void pv_mfma(
    const float* __restrict__ P, const unsigned short* __restrict__ Vt,
    unsigned short* __restrict__ Hb)
{
    __shared__ __attribute__((aligned(16))) unsigned short Ps[128 * 32];
    __shared__ __attribute__((aligned(16))) unsigned short Vs[64 * 32];
    const int t = threadIdx.x, lane = t & 63, w = t >> 6;
    const int bh = blockIdx.y, b = bh >> 3, h = bh & 7;
    const int q0 = blockIdx.x * 128;
    f32x4 acc[2][4];
#pragma unroll
    for (int m = 0; m < 2; ++m)
#pragma unroll
        for (int n = 0; n < 4; ++n) acc[m][n] = (f32x4){0.f, 0.f, 0.f, 0.f};

    for (int kc = 0; kc < 1024; kc += 32) {
#pragma unroll
        for (int i = 0; i < 4; ++i) {       // reg-stage P fp32 -> bf16
            int f = i * 256 + t;
            int row = f >> 3, c = f & 7;
            float4 pv = *(const float4*)(P + ((size_t)(bh * 1024 + q0 + row)) * 1024 + kc + c * 4);
            short4v pk;
            pk.x = f2bf(pv.x); pk.y = f2bf(pv.y); pk.z = f2bf(pv.z); pk.w = f2bf(pv.w);
            *(short4v*)&Ps[row * 32 + c * 4] = pk;
        }
        async16(Vt + ((size_t)bh * 64 + w * 16 + (lane >> 2)) * 1024 + kc + (lane & 3) * 8,
                &Vs[w * 512]);
        __syncthreads();
        short8v a[2], bb[4];
#pragma unroll
        for (int m = 0; m < 2; ++m)
            a[m] = *(const short8v*)&Ps[(w * 32 + m * 16 + (lane & 15)) * 32 + (lane >> 4) * 8];
#pragma unroll
        for (int n = 0; n < 4; ++n)
            bb[n] = *(const short8v*)&Vs[(n * 16 + (lane & 15)) * 32 + (lane >> 4) * 8];
#pragma unroll
        for (int m = 0; m < 2; ++m)
#pragma unroll
            for (int n = 0; n < 4; ++n)
                acc[m][n] = mfma_bf16(a[m], bb[n], acc[m][n]);
        __syncthreads();
    }
#pragma unroll
    for (int m = 0; m < 2; ++m) {
        int gq = q0 + w * 32 + m * 16 + (lane >> 4) * 4;
#pragma unroll
        for (int n = 0; n < 4; ++n) {
            int gd = h * 64 + n * 16 + (lane & 15);
#pragma unroll
            for (int j = 0; j < 4; ++j)
                Hb[(size_t)(b * 1024 + gq + j) * 512 + gd] = f2bf(acc[m][n][j]);
        }
    }
}

// ---------------------------------------------------------------------------
// Row softmax over 1024 elems, in place (fp32). One block (256 thr) per row.
// ---------------------------------------------------------------------------
__global__ __launch_bounds__(256) void softmax1024(float* __restrict__ S)
{
    float* p = S + (size_t)blockIdx.x * 1024;
    const int t = threadIdx.x;
    float4 x = *(const float4*)(p + t * 4);
    float m = fmaxf(fmaxf(x.x, x.y), fmaxf(x.z, x.w));
#pragma unroll
    for (int o = 32; o > 0; o >>= 1) m = fmaxf(m, __shfl_xor(m, o));
    __shared__ float rmax[4], rsum[4];
    if ((t & 63) == 0) rmax[t >> 6] = m;
    __syncthreads();
    m = fmaxf(fmaxf(rmax[0], rmax[1]), fmaxf(rmax[2], rmax[3]));
    float4 e;
    e.x = expf(x.x - m); e.y = expf(x.y - m);
    e.z = expf(x.z - m); e.w = expf(x.w - m);
    float s = e.x + e.y + e.z + e.w;
#pragma unroll
    for (int o = 32; o > 0; o >>= 1) s += __shfl_xor(s, o);
    if ((t & 63) == 0) rsum[t >> 6] = s;
    __syncthreads();
    s = rsum[0] + rsum[1] + rsum[2] + rsum[3];
    float inv = 1.0f / s;
    e.x *= inv; e.y *= inv; e.z *= inv; e.w *= inv;
    *(float4*)(p + t * 4) = e;
}

// ---------------------------------------------------------------------------
// LayerNorm over 512: out = LN(Xp + Res)*g + be (+ optional bf16 copy).
// ---------------------------------------------------------------------------
__global__ __launch_bounds__(128) void ln512(
    const float* __restrict__ Xp, const float* __restrict__ Res,
    const float* __restrict__ g, const float* __restrict__ be,
    float* __restrict__ out, unsigned short* __restrict__ outb)
{
    const size_t row = blockIdx.x;
    const int t = threadIdx.x;
    float4 x = *(const float4*)(Xp + row * 512 + t * 4);
    float4 r = *(const float4*)(Res + row * 512 + t * 4);
    x.x += r.x; x.y += r.y; x.z += r.z; x.w += r.w;
    float s  = x.x + x.y + x.z + x.w;
    float ss = x.x * x.x + x.y * x.y + x.z * x.z + x.w * x.w;
#pragma unroll
    for (int o = 32; o > 0; o >>= 1) { s += __shfl_xor(s, o); ss += __shfl_xor(ss, o); }
    __shared__ float sm[2], sq[2];
    if ((t & 63) == 0) { sm[t >> 6] = s; sq[t >> 6] = ss; }
    __syncthreads();
    s = sm[0] + sm[1]; ss = sq[0] + sq[1];
    const float mean = s * (1.f / 512.f);
    const float var  = ss * (1.f / 512.f) - mean * mean;
    const float rstd = rsqrtf(var + 1e-3f);
    float4 gv = *(const float4*)(g + t * 4), bv = *(const float4*)(be + t * 4);
    float4 o;
    o.x = (x.x - mean) * rstd * gv.x + bv.x;
    o.y = (x.y - mean) * rstd * gv.y + bv.y;
    o.z = (x.z - mean) * rstd * gv.z + bv.z;
    o.w = (x.w - mean) * rstd * gv.w + bv.w;
    *(float4*)(out + row * 512 + t * 4) = o;
    if (outb) {
        short4v q4;
        q4.x = f2bf(o.x); q4.y = f2bf(o.y); q4.z = f2bf(o.z); q4.w = f2bf(o.w);
        *(short4v*)(outb + row * 512 + t * 4) = q4;
    }
}

// ---------------------------------------------------------------------------
// Weight transpose-cast: W[K][N] fp32 -> WT[N][K] bf16. Grid (N/64, K/64).
// ---------------------------------------------------------------------------
__global__ __launch_bounds__(256) void wt_cast(
    const float* __restrict__ W, unsigned short* __restrict__ WT, int K, int N)
{
    __shared__ float T[64][68];
    const int t = threadIdx.x;
    const int k0 = blockIdx.y * 64, n0 = blockIdx.x * 64;
    int r = t >> 4, c = (t & 15) * 4;
#pragma unroll
    for (int p = 0; p < 4; ++p) {
        float4 v = *(const float4*)(W + (size_t)(k0 + r + p * 16) * N + n0 + c);
        T[r + p * 16][c + 0] = v.x; T[r + p * 16][c + 1] = v.y;
        T[r + p * 16][c + 2] = v.z; T[r + p * 16][c + 3] = v.w;
    }
    __syncthreads();
#pragma unroll
    for (int p = 0; p < 4; ++p) {
        int n = r + p * 16;
        short4v o;
        o.x = f2bf(T[c + 0][n]); o.y = f2bf(T[c + 1][n]);
        o.z = f2bf(T[c + 2][n]); o.w = f2bf(T[c + 3][n]);
        *(short4v*)(WT + (size_t)(n0 + n) * K + k0 + c) = o;
    }
}

__global__ __launch_bounds__(256) void cast_bf16(
    const float* __restrict__ in, unsigned short* __restrict__ o, int n4)
{
    int i = blockIdx.x * 256 + threadIdx.x;
    if (i < n4) {
        float4 v = *(const float4*)(in + (size_t)i * 4);
        short4v s;
        s.x = f2bf(v.x); s.y = f2bf(v.y); s.z = f2bf(v.z); s.w = f2bf(v.w);
        *(short4v*)(o + (size_t)i * 4) = s;
    }
}

// ---------------------------------------------------------------------------

extern "C" void kernel_launch(void* const* d_in, const int* in_sizes, int n_in,
                              void* d_out, int out_size, void* d_ws, size_t ws_size,
                              hipStream_t stream)
{
    (void)in_sizes; (void)n_in; (void)out_size;
    const float* inputs    = (const float*)d_in[0];
    const float* enc_kv    = (const float*)d_in[1];
    const float* pad_mask  = (const float*)d_in[2];
    const float* look_mask = (const float*)d_in[3];
    const float* saWq  = (const float*)d_in[5];
    const float* sabq  = (const float*)d_in[6];
    const float* saWk  = (const float*)d_in[7];
    const float* sabk  = (const float*)d_in[8];
    const float* saWv  = (const float*)d_in[9];
    const float* sabv  = (const float*)d_in[10];
    const float* saWo  = (const float*)d_in[11];
    const float* sabo  = (const float*)d_in[12];
    const float* sarel = (const float*)d_in[13];
    const float* salg  = (const float*)d_in[14];
    const float* salb  = (const float*)d_in[15];
    const float* caWq  = (const float*)d_in[16];
    const float* cabq  = (const float*)d_in[17];
    const float* caWk  = (const float*)d_in[18];
    const float* cabk  = (const float*)d_in[19];
    const float* caWv  = (const float*)d_in[20];
    const float* cabv  = (const float*)d_in[21];
    const float* caWo  = (const float*)d_in[22];
    const float* cabo  = (const float*)d_in[23];
    const float* carel = (const float*)d_in[24];
    const float* calg  = (const float*)d_in[25];
    const float* calb  = (const float*)d_in[26];
    const float* fW1   = (const float*)d_in[27];
    const float* fb1   = (const float*)d_in[28];
    const float* fW2   = (const float*)d_in[29];
    const float* fb2   = (const float*)d_in[30];
    const float* flg   = (const float*)d_in[31];
    const float* flb   = (const float*)d_in[32];

    float* out    = (float*)d_out;
    float* attn_w = out + (size_t)8 * 1024 * 512;
    float* ca_w   = attn_w + (size_t)8 * 8 * 1024 * 1024;

    // ---- workspace layout (bytes) ----
    char* ws = (char*)d_ws;
    const size_t SZ_BF  = (size_t)8192 * 512 * 2;            // 8 MiB bf16 act
    const size_t SZ_F32 = (size_t)8192 * 512 * 4;            // 16 MiB fp32 act
    const size_t SZ_WT  = (size_t)4259968 * 2;               // all bf16 weights
    const size_t SZ_REL = (size_t)65536 * 513 * 2;           // 67.2 MB
    size_t off = 0;
    unsigned short* WTa = (unsigned short*)(ws + off); off += SZ_WT;
    unsigned short* Abf = (unsigned short*)(ws + off); off += SZ_BF;
    unsigned short* Qbf = (unsigned short*)(ws + off); off += SZ_BF;
    unsigned short* Kbf = (unsigned short*)(ws + off); off += SZ_BF;
    unsigned short* Vbf = (unsigned short*)(ws + off); off += SZ_BF;
    unsigned short* x1bf = (unsigned short*)(ws + off); off += SZ_BF;
    unsigned short* relqb = (unsigned short*)(ws + off); off += SZ_REL;
    float* x1 = (float*)(ws + off); off += SZ_F32;
    float* x2 = (float*)(ws + off); off += SZ_F32;
    float* Pb = (float*)(ws + off); off += SZ_F32;
    if (ws_size < off) {
        fprintf(stderr, "kernel_launch: ws too small (%zu < %zu)\n", ws_size, off);
        return;
    }
    // weight sub-buffers (elements)
    unsigned short* saWqT = WTa + 0;
    unsigned short* saWkT = WTa + 262144;
    unsigned short* saWvT = WTa + 524288;
    unsigned short* saWoT = WTa + 786432;
    unsigned short* caWqT = WTa + 1048576;
    unsigned short* caWkT = WTa + 1310720;
    unsigned short* caWvT = WTa + 1572864;
    unsigned short* caWoT = WTa + 1835008;
    unsigned short* W1T   = WTa + 2097152;
    unsigned short* W2T   = WTa + 3145728;
    unsigned short* relSA = WTa + 4194304;
    unsigned short* relCA = WTa + 4227136;
    // aliases (disjoint lifetimes)
    unsigned short* headsbf = Qbf;           // PV out, then Wo-GEMM A
    unsigned short* Vt      = Kbf;           // after scores consumed K
    unsigned short* hiddenb = relqb;         // FFN hidden (33.5 MB < 67.2)
    unsigned short* x2bf    = Abf;           // after enc_kv bf16 dead

    const dim3 T256(256), T128(128);

    // ---- prep: weights ----
    wt_cast<<<dim3(8, 8),  T256, 0, stream>>>(saWq, saWqT, 512, 512);
    wt_cast<<<dim3(8, 8),  T256, 0, stream>>>(saWk, saWkT, 512, 512);
    wt_cast<<<dim3(8, 8),  T256, 0, stream>>>(saWv, saWvT, 512, 512);
    wt_cast<<<dim3(8, 8),  T256, 0, stream>>>(saWo, saWoT, 512, 512);
    wt_cast<<<dim3(8, 8),  T256, 0, stream>>>(caWq, caWqT, 512, 512);
    wt_cast<<<dim3(8, 8),  T256, 0, stream>>>(caWk, caWkT, 512, 512);
    wt_cast<<<dim3(8, 8),  T256, 0, stream>>>(caWv, caWvT, 512, 512);
    wt_cast<<<dim3(8, 8),  T256, 0, stream>>>(caWo, caWoT, 512, 512);
    wt_cast<<<dim3(32, 8), T256, 0, stream>>>(fW1, W1T, 512, 2048);
    wt_cast<<<dim3(8, 32), T256, 0, stream>>>(fW2, W2T, 2048, 512);
    cast_bf16<<<dim3(33),   T256, 0, stream>>>(sarel, relSA, 8208);
    cast_bf16<<<dim3(33),   T256, 0, stream>>>(carel, relCA, 8208);
    cast_bf16<<<dim3(4096), T256, 0, stream>>>(inputs, Abf, 1048576);

    // ---- self attention ----
    gemm_bf16<<<dim3(4, 64), T256, 0, stream>>>(Abf, saWqT, sabq, nullptr, Qbf, 8192, 512, 512, 0);
    gemm_bf16<<<dim3(4, 64), T256, 0, stream>>>(Abf, saWkT, sabk, nullptr, Kbf, 8192, 512, 512, 0);
    gemm_bf16<<<dim3(4, 64), T256, 0, stream>>>(Abf, saWvT, sabv, nullptr, Vbf, 8192, 512, 512, 0);
    relq_mfma<<<dim3(5, 512), T256, 0, stream>>>(Qbf, relSA, relqb);
    scores_mfma<<<dim3(8, 8, 64), T256, 0, stream>>>(Qbf, Kbf, relqb, look_mask, attn_w);
    transpose_v<<<dim3(8, 64), T256, 0, stream>>>(Vbf, Vt);
    softmax1024<<<dim3(65536), T256, 0, stream>>>(attn_w);
    pv_mfma<<<dim3(8, 64), T256, 0, stream>>>(attn_w, Vt, headsbf);
    gemm_bf16<<<dim3(4, 64), T256, 0, stream>>>(headsbf, saWoT, sabo, Pb, nullptr, 8192, 512, 512, 0);
    ln512<<<dim3(8192), T128, 0, stream>>>(Pb, inputs, salg, salb, x1, x1bf);

    // ---- cross attention ----
    cast_bf16<<<dim3(4096), T256, 0, stream>>>(enc_kv, Abf, 1048576);
    gemm_bf16<<<dim3(4, 64), T256, 0, stream>>>(x1bf, caWqT, cabq, nullptr, Qbf, 8192, 512, 512, 0);
    gemm_bf16<<<dim3(4, 64), T256, 0, stream>>>(Abf, caWkT, cabk, nullptr, Kbf, 8192, 512, 512, 0);
    gemm_bf16<<<dim3(4, 64), T256, 0, stream>>>(Abf, caWvT, cabv, nullptr, Vbf, 8192, 512, 512, 0);
    relq_mfma<<<dim3(5, 512), T256, 0, stream>>>(Qbf, relCA, relqb);
    scores_mfma<<<dim3(8, 8, 64), T256, 0, stream>>>(Qbf, Kbf, relqb, pad_mask, ca_w);
    transpose_v<<<dim3(8, 64), T256, 0, stream>>>(Vbf, Vt);
    softmax1024<<<dim3(65536), T256, 0, stream>>>(ca_w);
    pv_mfma<<<dim3(8, 64), T256, 0, stream>>>(ca_w, Vt, headsbf);
    gemm_bf16<<<dim3(4, 64), T256, 0, stream>>>(headsbf, caWoT, cabo, Pb, nullptr, 8192, 512, 512, 0);
    ln512<<<dim3(8192), T128, 0, stream>>>(Pb, x1, calg, calb, x2, x2bf);

    // ---- FFN ----
    gemm_bf16<<<dim3(16, 64), T256, 0, stream>>>(x2bf, W1T, fb1, nullptr, hiddenb, 8192, 2048, 512, 1);
    gemm_bf16<<<dim3(4, 64), T256, 0, stream>>>(hiddenb, W2T, fb2, Pb, nullptr, 8192, 512, 2048, 0);
    ln512<<<dim3(8192), T128, 0, stream>>>(Pb, x2, flg, flb, out, nullptr);
}

// Round 3
// 713.763 us; speedup vs baseline: 2.7034x; 1.3876x over previous
//
#include <hip/hip_runtime.h>
#include <hip/hip_bf16.h>
#include <cstdio>

// ---------------------------------------------------------------------------
// Decoder layer: B=8, L=1024, D=512, H=8, depth=64, FFN=2048, MAX_REL=256
// Outputs (fp32, concat): out[8,1024,512], attn_w[8,8,1024,1024], ca_w[same]
// Round 2: fused scores+softmax (in-kernel rel via MFMA), batched QKV GEMM.
// ---------------------------------------------------------------------------

typedef __attribute__((ext_vector_type(8))) short short8v;   // 8 bf16 (4 VGPR)
typedef __attribute__((ext_vector_type(4))) short short4v;   // 4 bf16 (8 B)
typedef __attribute__((ext_vector_type(4))) float f32x4;

static __device__ __forceinline__ unsigned short f2bf(float f) {
    unsigned int u = __float_as_uint(f);
    unsigned int r = (u + 0x7fffu + ((u >> 16) & 1u)) >> 16;
    return (unsigned short)r;
}
static __device__ __forceinline__ float bf2f(unsigned short s) {
    return __uint_as_float(((unsigned int)s) << 16);
}

static __device__ __forceinline__ f32x4 mfma_bf16(short8v a, short8v b, f32x4 c) {
    return __builtin_amdgcn_mfma_f32_16x16x32_bf16(a, b, c, 0, 0, 0);
}

// async global->LDS, 16B per lane. LDS dest: wave-uniform base + lane*16.
static __device__ __forceinline__ void async16(const void* g, void* l) {
    __builtin_amdgcn_global_load_lds(
        (const __attribute__((address_space(1))) unsigned int*)g,
        (__attribute__((address_space(3))) unsigned int*)l,
        16, 0, 0);
}

// Fragment conventions for mfma_f32_16x16x32_bf16 (verified in round 1):
//   A-frag: lane holds A[row = lane&15][k = (lane>>4)*8 + j]
//   B-frag: lane holds B[k][col = lane&15] (read from B^T rows)
//   C/D   : col = lane&15, row = (lane>>4)*4 + reg

// ---------------------------------------------------------------------------
// Generic bf16 MFMA GEMM: C[M,N] = A[M,K] @ BT[N,K]^T + bias
// Tile 128x128, BK=32, 256 threads (4 waves, 2x2), global_load_lds staging.
// ---------------------------------------------------------------------------
__global__ __launch_bounds__(256) void gemm_bf16(
    const unsigned short* __restrict__ A, const unsigned short* __restrict__ BT,
    const float* __restrict__ bias, float* __restrict__ Cf,
    unsigned short* __restrict__ Cb, int M, int N, int K, int relu)
{
    __shared__ __attribute__((aligned(16))) unsigned short As[128 * 32];
    __shared__ __attribute__((aligned(16))) unsigned short Bs[128 * 32];
    const int t = threadIdx.x, lane = t & 63, w = t >> 6;
    const int wm = w >> 1, wn = w & 1;
    const int m0 = blockIdx.y * 128, n0 = blockIdx.x * 128;
    f32x4 acc[4][4];
#pragma unroll
    for (int m = 0; m < 4; ++m)
#pragma unroll
        for (int n = 0; n < 4; ++n) acc[m][n] = (f32x4){0.f, 0.f, 0.f, 0.f};

    const int srow = lane >> 2, sg = lane & 3;
    for (int k0 = 0; k0 < K; k0 += 32) {
#pragma unroll
        for (int c = w; c < 8; c += 4) {
            async16(A  + (size_t)(m0 + c * 16 + srow) * K + k0 + sg * 8, &As[c * 512]);
            async16(BT + (size_t)(n0 + c * 16 + srow) * K + k0 + sg * 8, &Bs[c * 512]);
        }
        __syncthreads();
        short8v a[4], b[4];
#pragma unroll
        for (int m = 0; m < 4; ++m)
            a[m] = *(const short8v*)&As[(wm * 64 + m * 16 + (lane & 15)) * 32 + (lane >> 4) * 8];
#pragma unroll
        for (int n = 0; n < 4; ++n)
            b[n] = *(const short8v*)&Bs[(wn * 64 + n * 16 + (lane & 15)) * 32 + (lane >> 4) * 8];
#pragma unroll
        for (int m = 0; m < 4; ++m)
#pragma unroll
            for (int n = 0; n < 4; ++n)
                acc[m][n] = mfma_bf16(a[m], b[n], acc[m][n]);
        __syncthreads();
    }
#pragma unroll
    for (int m = 0; m < 4; ++m) {
        int gm = m0 + wm * 64 + m * 16 + (lane >> 4) * 4;
#pragma unroll
        for (int n = 0; n < 4; ++n) {
            int gn = n0 + wn * 64 + n * 16 + (lane & 15);
            float bv = bias ? bias[gn] : 0.f;
#pragma unroll
            for (int j = 0; j < 4; ++j) {
                float v = acc[m][n][j] + bv;
                if (relu) v = fmaxf(v, 0.f);
                size_t off = (size_t)(gm + j) * N + gn;
                if (Cf) Cf[off] = v;
                if (Cb) Cb[off] = f2bf(v);
            }
        }
    }
}

// ---------------------------------------------------------------------------
// Fused scores + softmax. One block per (bh, 16 q-rows). 256 thr = 4 waves.
// Wave w covers k columns {qtr*256 + w*64 + n*16 + lane&15}.
// In-kernel rel-logits tile (16 x 513) via MFMA from rel_emb [513][64] bf16.
// Writes final normalized weights (fp32) once.
// ---------------------------------------------------------------------------
__global__ __launch_bounds__(256) void fused_attn(
    const unsigned short* __restrict__ Qp, int qstride,
    const unsigned short* __restrict__ Kp, int kstride,
    const unsigned short* __restrict__ relW,   // [513][64] bf16
    const float* __restrict__ mask,            // [8][1024][1024] fp32
    float* __restrict__ Wout)                  // [64][1024][1024] fp32
{
    __shared__ __attribute__((aligned(16))) unsigned short Qs[16 * 64];    // 2 KB
    __shared__ __attribute__((aligned(16))) unsigned short Rel[16 * 528];  // 16.5 KB
    __shared__ __attribute__((aligned(16))) unsigned short Ks[256 * 64];   // 32 KB
    __shared__ float Red[2][4][16];                                        // 512 B
    const int t = threadIdx.x, lane = t & 63, w = t >> 6;
    const int bh = blockIdx.y, b = bh >> 3, h = bh & 7;
    const int q0 = blockIdx.x * 16;

    // stage Q tile (16 rows x 64) : waves 0,1 stage 8 rows each
    if (w < 2)
        async16(Qp + (size_t)(b * 1024 + q0 + w * 8 + (lane >> 3)) * qstride
                   + h * 64 + (lane & 7) * 8,
                &Qs[w * 8 * 64]);
    __syncthreads();

    short8v qa[2];
#pragma unroll
    for (int kk = 0; kk < 2; ++kk)
        qa[kk] = *(const short8v*)&Qs[(lane & 15) * 64 + kk * 32 + (lane >> 4) * 8];

    // rel tile: 33 16x16 tiles over r, B-frags read directly from global relW
    for (int rs = w; rs < 33; rs += 4) {
        int rc = rs * 16 + (lane & 15);
        int re = rc > 512 ? 512 : rc;              // clamp (cols >512 unused)
        short8v b0 = *(const short8v*)(relW + (size_t)re * 64 + (lane >> 4) * 8);
        short8v b1 = *(const short8v*)(relW + (size_t)re * 64 + 32 + (lane >> 4) * 8);
        f32x4 r4 = (f32x4){0.f, 0.f, 0.f, 0.f};
        r4 = mfma_bf16(qa[0], b0, r4);
        r4 = mfma_bf16(qa[1], b1, r4);
#pragma unroll
        for (int j = 0; j < 4; ++j)
            Rel[((lane >> 4) * 4 + j) * 528 + rs * 16 + (lane & 15)] = f2bf(r4[j]);
    }
    __syncthreads();

    // scores: loop 4 quarters of 256 k-rows staged in LDS
    f32x4 acc[16];
#pragma unroll
    for (int i = 0; i < 16; ++i) acc[i] = (f32x4){0.f, 0.f, 0.f, 0.f};

#pragma unroll
    for (int qtr = 0; qtr < 4; ++qtr) {
#pragma unroll
        for (int c = 0; c < 8; ++c) {
            int rbase = w * 64 + c * 8;
            async16(Kp + (size_t)(b * 1024 + qtr * 256 + rbase + (lane >> 3)) * kstride
                       + h * 64 + (lane & 7) * 8,
                    &Ks[rbase * 64]);
        }
        __syncthreads();
#pragma unroll
        for (int n = 0; n < 4; ++n) {
            short8v kb0 = *(const short8v*)&Ks[(w * 64 + n * 16 + (lane & 15)) * 64 + (lane >> 4) * 8];
            short8v kb1 = *(const short8v*)&Ks[(w * 64 + n * 16 + (lane & 15)) * 64 + 32 + (lane >> 4) * 8];
            acc[qtr * 4 + n] = mfma_bf16(qa[0], kb0, acc[qtr * 4 + n]);
            acc[qtr * 4 + n] = mfma_bf16(qa[1], kb1, acc[qtr * 4 + n]);
        }
        __syncthreads();
    }

    // finalize scores: + rel, * 1/8, + mask * -1e9
    const int qb = q0 + (lane >> 4) * 4;     // global q for j=0
    const int ql = (lane >> 4) * 4;          // local q for j=0
    const float* mrow = mask + ((size_t)b * 1024 + qb) * 1024;
#pragma unroll
    for (int na = 0; na < 16; ++na) {
        int k = (na >> 2) * 256 + w * 64 + (na & 3) * 16 + (lane & 15);
#pragma unroll
        for (int j = 0; j < 4; ++j) {
            int q = qb + j;
            int d = k - q; d = d < -256 ? -256 : (d > 256 ? 256 : d);
            float rel = bf2f(Rel[(ql + j) * 528 + d + 256]);
            float mv = mrow[(size_t)j * 1024 + k];
            acc[na][j] = (acc[na][j] + rel) * 0.125f + mv * (-1e9f);
        }
    }

    // row max: lane-local over 16 na, then 16-lane group shuffle, then x-wave
    float mx[4];
#pragma unroll
    for (int j = 0; j < 4; ++j) {
        float m = acc[0][j];
#pragma unroll
        for (int na = 1; na < 16; ++na) m = fmaxf(m, acc[na][j]);
#pragma unroll
        for (int off = 1; off < 16; off <<= 1) m = fmaxf(m, __shfl_xor(m, off));
        mx[j] = m;
    }
    if ((lane & 15) == 0) {
#pragma unroll
        for (int j = 0; j < 4; ++j) Red[0][w][ql + j] = mx[j];
    }
    __syncthreads();
#pragma unroll
    for (int j = 0; j < 4; ++j) {
        float m = Red[0][0][ql + j];
        m = fmaxf(m, Red[0][1][ql + j]);
        m = fmaxf(m, Red[0][2][ql + j]);
        m = fmaxf(m, Red[0][3][ql + j]);
        mx[j] = m;
    }

    // exp + row sum
    float sm[4] = {0.f, 0.f, 0.f, 0.f};
#pragma unroll
    for (int na = 0; na < 16; ++na)
#pragma unroll
        for (int j = 0; j < 4; ++j) {
            float e = __expf(acc[na][j] - mx[j]);
            acc[na][j] = e;
            sm[j] += e;
        }
#pragma unroll
    for (int j = 0; j < 4; ++j)
#pragma unroll
        for (int off = 1; off < 16; off <<= 1) sm[j] += __shfl_xor(sm[j], off);
    if ((lane & 15) == 0) {
#pragma unroll
        for (int j = 0; j < 4; ++j) Red[1][w][ql + j] = sm[j];
    }
    __syncthreads();
#pragma unroll
    for (int j = 0; j < 4; ++j) {
        float s = Red[1][0][ql + j] + Red[1][1][ql + j]
                + Red[1][2][ql + j] + Red[1][3][ql + j];
        sm[j] = 1.0f / s;
    }

    // normalize + single fp32 write of the weights
    float* wbase = Wout + ((size_t)bh * 1024 + qb) * 1024;
#pragma unroll
    for (int na = 0; na < 16; ++na) {
        int k = (na >> 2) * 256 + w * 64 + (na & 3) * 16 + (lane & 15);
#pragma unroll
        for (int j = 0; j < 4; ++j)
            wbase[(size_t)j * 1024 + k] = acc[na][j] * sm[j];
    }
}

// ---------------------------------------------------------------------------
// V transpose per head: V[b,k,h*64+d] (bf16, given row stride) -> Vt[bh,d,k]
// Grid (8 k-tiles(128), 64 bh).
// ---------------------------------------------------------------------------
__global__ __launch_bounds__(256) void transpose_v(
    const unsigned short* __restrict__ Vb, int stride, unsigned short* __restrict__ Vt)
{
    __shared__ unsigned short T[128][72];
    const int bh = blockIdx.y, b = bh >> 3, h = bh & 7;
    const int k0 = blockIdx.x * 128;
    const int t = threadIdx.x;
    {
        int r = t >> 1, half = t & 1;
        const unsigned short* gp = Vb + (size_t)(b * 1024 + k0 + r) * stride + h * 64 + half * 32;
#pragma unroll
        for (int i = 0; i < 8; ++i)
            *(short4v*)&T[r][half * 32 + i * 4] = *(const short4v*)(gp + i * 4);
    }
    __syncthreads();
    {
        int d = t >> 2, qtr = t & 3;
        unsigned short* gp = Vt + ((size_t)bh * 64 + d) * 1024 + k0 + qtr * 32;
#pragma unroll
        for (int i = 0; i < 32; i += 4) {
            short4v v;
            v.x = T[qtr * 32 + i + 0][d];
            v.y = T[qtr * 32 + i + 1][d];
            v.z = T[qtr * 32 + i + 2][d];
            v.w = T[qtr * 32 + i + 3][d];
            *(short4v*)(gp + i) = v;
        }
    }
}

// ---------------------------------------------------------------------------
// PV: heads[b,q,h*64+d] = sum_k P[bh,q,k] * V[b,k,h*64+d]; P fp32 -> bf16.
// Tile 128q x 64d, BK=32. Grid (8, 64 bh).
// ---------------------------------------------------------------------------
__global__ __launch_bounds__(256) void pv_mfma(
    const float* __restrict__ P, const unsigned short* __restrict__ Vt,
    unsigned short* __restrict__ Hb)
{
    __shared__ __attribute__((aligned(16))) unsigned short Ps[128 * 32];
    __shared__ __attribute__((aligned(16))) unsigned short Vs[64 * 32];
    const int t = threadIdx.x, lane = t & 63, w = t >> 6;
    const int bh = blockIdx.y, b = bh >> 3, h = bh & 7;
    const int q0 = blockIdx.x * 128;
    f32x4 acc[2][4];
#pragma unroll
    for (int m = 0; m < 2; ++m)
#pragma unroll
        for (int n = 0; n < 4; ++n) acc[m][n] = (f32x4){0.f, 0.f, 0.f, 0.f};

    for (int kc = 0; kc < 1024; kc += 32) {
#pragma unroll
        for (int i = 0; i < 4; ++i) {
            int f = i * 256 + t;
            int row = f >> 3, c = f & 7;
            float4 pv = *(const float4*)(P + ((size_t)(bh * 1024 + q0 + row)) * 1024 + kc + c * 4);
            short4v pk;
            pk.x = f2bf(pv.x); pk.y = f2bf(pv.y); pk.z = f2bf(pv.z); pk.w = f2bf(pv.w);
            *(short4v*)&Ps[row * 32 + c * 4] = pk;
        }
        async16(Vt + ((size_t)bh * 64 + w * 16 + (lane >> 2)) * 1024 + kc + (lane & 3) * 8,
                &Vs[w * 512]);
        __syncthreads();
        short8v a[2], bb[4];
#pragma unroll
        for (int m = 0; m < 2; ++m)
            a[m] = *(const short8v*)&Ps[(w * 32 + m * 16 + (lane & 15)) * 32 + (lane >> 4) * 8];
#pragma unroll
        for (int n = 0; n < 4; ++n)
            bb[n] = *(const short8v*)&Vs[(n * 16 + (lane & 15)) * 32 + (lane >> 4) * 8];
#pragma unroll
        for (int m = 0; m < 2; ++m)
#pragma unroll
            for (int n = 0; n < 4; ++n)
                acc[m][n] = mfma_bf16(a[m], bb[n], acc[m][n]);
        __syncthreads();
    }
#pragma unroll
    for (int m = 0; m < 2; ++m) {
        int gq = q0 + w * 32 + m * 16 + (lane >> 4) * 4;
#pragma unroll
        for (int n = 0; n < 4; ++n) {
            int gd = h * 64 + n * 16 + (lane & 15);
#pragma unroll
            for (int j = 0; j < 4; ++j)
                Hb[(size_t)(b * 1024 + gq + j) * 512 + gd] = f2bf(acc[m][n][j]);
        }
    }
}

// ---------------------------------------------------------------------------
// LayerNorm over 512: out = LN(Xp + Res)*g + be (+ optional bf16 copy).
// ---------------------------------------------------------------------------
__global__ __launch_bounds__(128) void ln512(
    const float* __restrict__ Xp, const float* __restrict__ Res,
    const float* __restrict__ g, const float* __restrict__ be,
    float* __restrict__ out, unsigned short* __restrict__ outb)
{
    const size_t row = blockIdx.x;
    const int t = threadIdx.x;
    float4 x = *(const float4*)(Xp + row * 512 + t * 4);
    float4 r = *(const float4*)(Res + row * 512 + t * 4);
    x.x += r.x; x.y += r.y; x.z += r.z; x.w += r.w;
    float s  = x.x + x.y + x.z + x.w;
    float ss = x.x * x.x + x.y * x.y + x.z * x.z + x.w * x.w;
#pragma unroll
    for (int o = 32; o > 0; o >>= 1) { s += __shfl_xor(s, o); ss += __shfl_xor(ss, o); }
    __shared__ float sm[2], sq[2];
    if ((t & 63) == 0) { sm[t >> 6] = s; sq[t >> 6] = ss; }
    __syncthreads();
    s = sm[0] + sm[1]; ss = sq[0] + sq[1];
    const float mean = s * (1.f / 512.f);
    const float var  = ss * (1.f / 512.f) - mean * mean;
    const float rstd = rsqrtf(var + 1e-3f);
    float4 gv = *(const float4*)(g + t * 4), bv = *(const float4*)(be + t * 4);
    float4 o;
    o.x = (x.x - mean) * rstd * gv.x + bv.x;
    o.y = (x.y - mean) * rstd * gv.y + bv.y;
    o.z = (x.z - mean) * rstd * gv.z + bv.z;
    o.w = (x.w - mean) * rstd * gv.w + bv.w;
    *(float4*)(out + row * 512 + t * 4) = o;
    if (outb) {
        short4v q4;
        q4.x = f2bf(o.x); q4.y = f2bf(o.y); q4.z = f2bf(o.z); q4.w = f2bf(o.w);
        *(short4v*)(outb + row * 512 + t * 4) = q4;
    }
}

// ---------------------------------------------------------------------------
// Weight transpose-cast: W[K][N] fp32 -> WT[N][K] bf16. Grid (N/64, K/64).
// ---------------------------------------------------------------------------
__global__ __launch_bounds__(256) void wt_cast(
    const float* __restrict__ W, unsigned short* __restrict__ WT, int K, int N)
{
    __shared__ float T[64][68];
    const int t = threadIdx.x;
    const int k0 = blockIdx.y * 64, n0 = blockIdx.x * 64;
    int r = t >> 4, c = (t & 15) * 4;
#pragma unroll
    for (int p = 0; p < 4; ++p) {
        float4 v = *(const float4*)(W + (size_t)(k0 + r + p * 16) * N + n0 + c);
        T[r + p * 16][c + 0] = v.x; T[r + p * 16][c + 1] = v.y;
        T[r + p * 16][c + 2] = v.z; T[r + p * 16][c + 3] = v.w;
    }
    __syncthreads();
#pragma unroll
    for (int p = 0; p < 4; ++p) {
        int n = r + p * 16;
        short4v o;
        o.x = f2bf(T[c + 0][n]); o.y = f2bf(T[c + 1][n]);
        o.z = f2bf(T[c + 2][n]); o.w = f2bf(T[c + 3][n]);
        *(short4v*)(WT + (size_t)(n0 + n) * K + k0 + c) = o;
    }
}

__global__ __launch_bounds__(256) void cast_bf16(
    const float* __restrict__ in, unsigned short* __restrict__ o, int n4)
{
    int i = blockIdx.x * 256 + threadIdx.x;
    if (i < n4) {
        float4 v = *(const float4*)(in + (size_t)i * 4);
        short4v s;
        s.x = f2bf(v.x); s.y = f2bf(v.y); s.z = f2bf(v.z); s.w = f2bf(v.w);
        *(short4v*)(o + (size_t)i * 4) = s;
    }
}

// pack up to 3 512-long bias vectors into one contiguous fp32 buffer
__global__ __launch_bounds__(256) void pack_bias(
    float* __restrict__ o, const float* __restrict__ a,
    const float* __restrict__ b, const float* __restrict__ c, int n)
{
    int i = blockIdx.x * 256 + threadIdx.x;
    if (i >= n) return;
    float v;
    if (i < 512) v = a[i];
    else if (i < 1024) v = b[i - 512];
    else v = c[i - 1024];
    o[i] = v;
}

// ---------------------------------------------------------------------------

extern "C" void kernel_launch(void* const* d_in, const int* in_sizes, int n_in,
                              void* d_out, int out_size, void* d_ws, size_t ws_size,
                              hipStream_t stream)
{
    (void)in_sizes; (void)n_in; (void)out_size;
    const float* inputs    = (const float*)d_in[0];
    const float* enc_kv    = (const float*)d_in[1];
    const float* pad_mask  = (const float*)d_in[2];
    const float* look_mask = (const float*)d_in[3];
    const float* saWq  = (const float*)d_in[5];
    const float* sabq  = (const float*)d_in[6];
    const float* saWk  = (const float*)d_in[7];
    const float* sabk  = (const float*)d_in[8];
    const float* saWv  = (const float*)d_in[9];
    const float* sabv  = (const float*)d_in[10];
    const float* saWo  = (const float*)d_in[11];
    const float* sabo  = (const float*)d_in[12];
    const float* sarel = (const float*)d_in[13];
    const float* salg  = (const float*)d_in[14];
    const float* salb  = (const float*)d_in[15];
    const float* caWq  = (const float*)d_in[16];
    const float* cabq  = (const float*)d_in[17];
    const float* caWk  = (const float*)d_in[18];
    const float* cabk  = (const float*)d_in[19];
    const float* caWv  = (const float*)d_in[20];
    const float* cabv  = (const float*)d_in[21];
    const float* caWo  = (const float*)d_in[22];
    const float* cabo  = (const float*)d_in[23];
    const float* carel = (const float*)d_in[24];
    const float* calg  = (const float*)d_in[25];
    const float* calb  = (const float*)d_in[26];
    const float* fW1   = (const float*)d_in[27];
    const float* fb1   = (const float*)d_in[28];
    const float* fW2   = (const float*)d_in[29];
    const float* fb2   = (const float*)d_in[30];
    const float* flg   = (const float*)d_in[31];
    const float* flb   = (const float*)d_in[32];

    float* out    = (float*)d_out;
    float* attn_w = out + (size_t)8 * 1024 * 512;
    float* ca_w   = attn_w + (size_t)8 * 8 * 1024 * 1024;

    // ---- workspace layout ----
    char* ws = (char*)d_ws;
    size_t off = 0;
    unsigned short* WTa = (unsigned short*)(ws + off); off += 8519936;   // weights bf16
    float* bqkv = (float*)(ws + off); off += 8192;                       // packed sa q|k|v bias
    float* bkv  = (float*)(ws + off); off += 8192;                       // packed ca k|v bias
    unsigned short* Abf   = (unsigned short*)(ws + off); off += 8388608; // act bf16 [8192][512]
    unsigned short* x1bf  = (unsigned short*)(ws + off); off += 8388608;
    unsigned short* Qca   = (unsigned short*)(ws + off); off += 8388608;
    unsigned short* heads = (unsigned short*)(ws + off); off += 8388608;
    unsigned short* Vt    = (unsigned short*)(ws + off); off += 8388608; // [64][64][1024]
    unsigned short* KV    = (unsigned short*)(ws + off); off += 16777216;// [8192][1024]
    unsigned short* big   = (unsigned short*)(ws + off); off += 33554432;// QKV / FFN hidden
    float* x1 = (float*)(ws + off); off += 16777216;
    float* x2 = (float*)(ws + off); off += 16777216;
    float* Pb = (float*)(ws + off); off += 16777216;
    if (ws_size < off) {
        fprintf(stderr, "kernel_launch: ws too small (%zu < %zu)\n", ws_size, off);
        return;
    }
    unsigned short* QKV    = big;                 // [8192][1536] (SA only)
    unsigned short* hidden = big;                 // [8192][2048] (FFN only)
    unsigned short* x2bf   = Abf;                 // alias: enc bf16 dead by then

    // weight sub-buffers inside WTa (contiguity gives fused-QKV BT for free)
    unsigned short* saWqT = WTa + 0;              // rows 0-511   of [1536][512]
    unsigned short* saWkT = WTa + 262144;         // rows 512-1023
    unsigned short* saWvT = WTa + 524288;         // rows 1024-1535
    unsigned short* saWoT = WTa + 786432;
    unsigned short* caWqT = WTa + 1048576;
    unsigned short* caWkT = WTa + 1310720;        // rows 0-511   of [1024][512]
    unsigned short* caWvT = WTa + 1572864;        // rows 512-1023
    unsigned short* caWoT = WTa + 1835008;
    unsigned short* W1T   = WTa + 2097152;
    unsigned short* W2T   = WTa + 3145728;
    unsigned short* relSA = WTa + 4194304;
    unsigned short* relCA = WTa + 4227136;

    const dim3 T256(256), T128(128);

    // ---- prep ----
    wt_cast<<<dim3(8, 8),  T256, 0, stream>>>(saWq, saWqT, 512, 512);
    wt_cast<<<dim3(8, 8),  T256, 0, stream>>>(saWk, saWkT, 512, 512);
    wt_cast<<<dim3(8, 8),  T256, 0, stream>>>(saWv, saWvT, 512, 512);
    wt_cast<<<dim3(8, 8),  T256, 0, stream>>>(saWo, saWoT, 512, 512);
    wt_cast<<<dim3(8, 8),  T256, 0, stream>>>(caWq, caWqT, 512, 512);
    wt_cast<<<dim3(8, 8),  T256, 0, stream>>>(caWk, caWkT, 512, 512);
    wt_cast<<<dim3(8, 8),  T256, 0, stream>>>(caWv, caWvT, 512, 512);
    wt_cast<<<dim3(8, 8),  T256, 0, stream>>>(caWo, caWoT, 512, 512);
    wt_cast<<<dim3(32, 8), T256, 0, stream>>>(fW1, W1T, 512, 2048);
    wt_cast<<<dim3(8, 32), T256, 0, stream>>>(fW2, W2T, 2048, 512);
    cast_bf16<<<dim3(33),   T256, 0, stream>>>(sarel, relSA, 8208);
    cast_bf16<<<dim3(33),   T256, 0, stream>>>(carel, relCA, 8208);
    cast_bf16<<<dim3(4096), T256, 0, stream>>>(inputs, Abf, 1048576);
    pack_bias<<<dim3(6), T256, 0, stream>>>(bqkv, sabq, sabk, sabv, 1536);
    pack_bias<<<dim3(4), T256, 0, stream>>>(bkv, cabk, cabv, nullptr, 1024);

    // ---- self attention ----
    gemm_bf16<<<dim3(12, 64), T256, 0, stream>>>(Abf, saWqT, bqkv, nullptr, QKV, 8192, 1536, 512, 0);
    transpose_v<<<dim3(8, 64), T256, 0, stream>>>(QKV + 1024, 1536, Vt);
    fused_attn<<<dim3(64, 64), T256, 0, stream>>>(QKV, 1536, QKV + 512, 1536, relSA, look_mask, attn_w);
    pv_mfma<<<dim3(8, 64), T256, 0, stream>>>(attn_w, Vt, heads);
    gemm_bf16<<<dim3(4, 64), T256, 0, stream>>>(heads, saWoT, sabo, Pb, nullptr, 8192, 512, 512, 0);
    ln512<<<dim3(8192), T128, 0, stream>>>(Pb, inputs, salg, salb, x1, x1bf);

    // ---- cross attention ----
    cast_bf16<<<dim3(4096), T256, 0, stream>>>(enc_kv, Abf, 1048576);
    gemm_bf16<<<dim3(8, 64), T256, 0, stream>>>(Abf, caWkT, bkv, nullptr, KV, 8192, 1024, 512, 0);
    gemm_bf16<<<dim3(4, 64), T256, 0, stream>>>(x1bf, caWqT, cabq, nullptr, Qca, 8192, 512, 512, 0);
    transpose_v<<<dim3(8, 64), T256, 0, stream>>>(KV + 512, 1024, Vt);
    fused_attn<<<dim3(64, 64), T256, 0, stream>>>(Qca, 512, KV, 1024, relCA, pad_mask, ca_w);
    pv_mfma<<<dim3(8, 64), T256, 0, stream>>>(ca_w, Vt, heads);
    gemm_bf16<<<dim3(4, 64), T256, 0, stream>>>(heads, caWoT, cabo, Pb, nullptr, 8192, 512, 512, 0);
    ln512<<<dim3(8192), T128, 0, stream>>>(Pb, x1, calg, calb, x2, x2bf);

    // ---- FFN ----
    gemm_bf16<<<dim3(16, 64), T256, 0, stream>>>(x2bf, W1T, fb1, nullptr, hidden, 8192, 2048, 512, 1);
    gemm_bf16<<<dim3(4, 64), T256, 0, stream>>>(hidden, W2T, fb2, Pb, nullptr, 8192, 512, 2048, 0);
    ln512<<<dim3(8192), T128, 0, stream>>>(Pb, x2, flg, flb, out, nullptr);
}

// Round 4
// 657.982 us; speedup vs baseline: 2.9326x; 1.0848x over previous
//
#include <hip/hip_runtime.h>
#include <hip/hip_bf16.h>
#include <cstdio>

// ---------------------------------------------------------------------------
// Decoder layer: B=8, L=1024, D=512, H=8, depth=64, FFN=2048, MAX_REL=256
// Outputs (fp32, concat): out[8,1024,512], attn_w[8,8,1024,1024], ca_w[same]
// Round 3: PV fused into attention kernel (P never re-read from global);
//          LDS slot-swizzles kill the 8/16-way ds_read bank conflicts.
// ---------------------------------------------------------------------------

typedef __attribute__((ext_vector_type(8))) short short8v;   // 8 bf16 (4 VGPR)
typedef __attribute__((ext_vector_type(4))) short short4v;   // 4 bf16 (8 B)
typedef __attribute__((ext_vector_type(4))) float f32x4;

static __device__ __forceinline__ unsigned short f2bf(float f) {
    unsigned int u = __float_as_uint(f);
    unsigned int r = (u + 0x7fffu + ((u >> 16) & 1u)) >> 16;
    return (unsigned short)r;
}
static __device__ __forceinline__ float bf2f(unsigned short s) {
    return __uint_as_float(((unsigned int)s) << 16);
}

static __device__ __forceinline__ f32x4 mfma_bf16(short8v a, short8v b, f32x4 c) {
    return __builtin_amdgcn_mfma_f32_16x16x32_bf16(a, b, c, 0, 0, 0);
}

// async global->LDS, 16B per lane. LDS dest: wave-uniform base + lane*16.
static __device__ __forceinline__ void async16(const void* g, void* l) {
    __builtin_amdgcn_global_load_lds(
        (const __attribute__((address_space(1))) unsigned int*)g,
        (__attribute__((address_space(3))) unsigned int*)l,
        16, 0, 0);
}

// Fragment conventions for mfma_f32_16x16x32_bf16 (verified rounds 1-2):
//   A-frag: lane holds A[row = lane&15][k = (lane>>4)*8 + j]
//   B-frag: lane holds B[k = (lane>>4)*8 + j][col = lane&15]
//   C/D   : col = lane&15, row = (lane>>4)*4 + reg
// LDS rows are divided into 16-B "slots"; stored slot = logical ^ swizzle(row)
// (applied on BOTH the pre-swizzled global source address of global_load_lds
//  and the ds_read side), spreading the 16-lane fragment reads across 8 banks.

// ---------------------------------------------------------------------------
// Generic bf16 MFMA GEMM: C[M,N] = A[M,K] @ BT[N,K]^T + bias
// Tile 128x128, BK=32, 256 threads (4 waves, 2x2), global_load_lds staging.
// Rows of As/Bs are 32 shorts = 4 slots; swizzle s = g ^ ((row>>1)&3).
// ---------------------------------------------------------------------------
__global__ __launch_bounds__(256) void gemm_bf16(
    const unsigned short* __restrict__ A, const unsigned short* __restrict__ BT,
    const float* __restrict__ bias, float* __restrict__ Cf,
    unsigned short* __restrict__ Cb, int M, int N, int K, int relu)
{
    __shared__ __attribute__((aligned(16))) unsigned short As[128 * 32];
    __shared__ __attribute__((aligned(16))) unsigned short Bs[128 * 32];
    const int t = threadIdx.x, lane = t & 63, w = t >> 6;
    const int wm = w >> 1, wn = w & 1;
    const int m0 = blockIdx.y * 128, n0 = blockIdx.x * 128;
    f32x4 acc[4][4];
#pragma unroll
    for (int m = 0; m < 4; ++m)
#pragma unroll
        for (int n = 0; n < 4; ++n) acc[m][n] = (f32x4){0.f, 0.f, 0.f, 0.f};

    // staging: lane covers row = c*16 + (l>>2), stored slot = l&3
    const int srow = lane >> 2;
    const int sgl  = (lane & 3) ^ ((lane >> 3) & 3);   // logical k-granule
    for (int k0 = 0; k0 < K; k0 += 32) {
#pragma unroll
        for (int c = w; c < 8; c += 4) {
            async16(A  + (size_t)(m0 + c * 16 + srow) * K + k0 + sgl * 8, &As[c * 512]);
            async16(BT + (size_t)(n0 + c * 16 + srow) * K + k0 + sgl * 8, &Bs[c * 512]);
        }
        __syncthreads();
        short8v a[4], b[4];
        const int g = lane >> 4, l15 = lane & 15;
        const int ss = (g ^ ((l15 >> 1) & 3)) * 8;
#pragma unroll
        for (int m = 0; m < 4; ++m)
            a[m] = *(const short8v*)&As[(wm * 64 + m * 16 + l15) * 32 + ss];
#pragma unroll
        for (int n = 0; n < 4; ++n)
            b[n] = *(const short8v*)&Bs[(wn * 64 + n * 16 + l15) * 32 + ss];
#pragma unroll
        for (int m = 0; m < 4; ++m)
#pragma unroll
            for (int n = 0; n < 4; ++n)
                acc[m][n] = mfma_bf16(a[m], b[n], acc[m][n]);
        __syncthreads();
    }
#pragma unroll
    for (int m = 0; m < 4; ++m) {
        int gm = m0 + wm * 64 + m * 16 + (lane >> 4) * 4;
#pragma unroll
        for (int n = 0; n < 4; ++n) {
            int gn = n0 + wn * 64 + n * 16 + (lane & 15);
            float bv = bias ? bias[gn] : 0.f;
#pragma unroll
            for (int j = 0; j < 4; ++j) {
                float v = acc[m][n][j] + bv;
                if (relu) v = fmaxf(v, 0.f);
                size_t off = (size_t)(gm + j) * N + gn;
                if (Cf) Cf[off] = v;
                if (Cb) Cb[off] = f2bf(v);
            }
        }
    }
}

// ---------------------------------------------------------------------------
// Fused scores + softmax + PV. One block per (bh, 16 q-rows). 256 thr = 4 waves.
//  - scores: wave w covers k cols {qtr*256 + w*64 + n*16 + lane&15}
//  - rel logits via MFMA from rel_emb, staged to LDS, gathered in epilogue
//  - softmax reductions: 16-lane shuffles + tiny cross-wave LDS
//  - normalized P written once to global (output) AND to LDS bf16
//  - PV: V chunks staged [64 d][128 k] (swizzled), wave w owns d-tile w*16
// LDS: Qs 2K + Rel 16.9K + U 48K (Ks 32K | Pl 32K + Vs 16K) + Red 0.5K = 67K
// ---------------------------------------------------------------------------
__global__ __launch_bounds__(256) void fused_attn(
    const unsigned short* __restrict__ Qp, int qstride,
    const unsigned short* __restrict__ Kp, int kstride,
    const unsigned short* __restrict__ Vt,     // [bh][64][1024] bf16
    const unsigned short* __restrict__ relW,   // [513][64] bf16
    const float* __restrict__ mask,            // [8][1024][1024] fp32
    float* __restrict__ Wout,                  // [64][1024][1024] fp32
    unsigned short* __restrict__ Hout)         // [8192][512] bf16
{
    __shared__ __attribute__((aligned(16))) unsigned short Qs[16 * 64];
    __shared__ __attribute__((aligned(16))) unsigned short Rel[16 * 528];
    __shared__ __attribute__((aligned(16))) unsigned short U[24576];  // 48 KB
    __shared__ float Red[2][4][16];
    unsigned short* Ks = U;              // [256][64] during scores
    unsigned short* Pl = U;              // [128 kg][16 q][8] after scores
    unsigned short* Vs = U + 16384;      // [64 d][128 k] (swizzled slots)
    const int t = threadIdx.x, lane = t & 63, w = t >> 6;
    const int g = lane >> 4, l15 = lane & 15;
    const int bh = blockIdx.y, b = bh >> 3, h = bh & 7;
    const int q0 = blockIdx.x * 16;

    // ---- stage Q tile (16 x 64), slot-swizzled (8 slots/row) ----
    if (w < 2) {
        int row = w * 8 + (lane >> 3);
        int gl = (lane & 7) ^ ((lane >> 3) & 7);
        async16(Qp + (size_t)(b * 1024 + q0 + row) * qstride + h * 64 + gl * 8,
                &Qs[w * 512]);
    }
    __syncthreads();

    short8v qa[2];
#pragma unroll
    for (int kk = 0; kk < 2; ++kk)
        qa[kk] = *(const short8v*)&Qs[l15 * 64 + (((kk * 4 + g) ^ (l15 & 7))) * 8];

    // ---- rel tile (16 x 513) via MFMA, B-frags straight from global ----
    for (int rs = w; rs < 33; rs += 4) {
        int rc = rs * 16 + l15;
        int re = rc > 512 ? 512 : rc;
        short8v b0 = *(const short8v*)(relW + (size_t)re * 64 + g * 8);
        short8v b1 = *(const short8v*)(relW + (size_t)re * 64 + 32 + g * 8);
        f32x4 r4 = (f32x4){0.f, 0.f, 0.f, 0.f};
        r4 = mfma_bf16(qa[0], b0, r4);
        r4 = mfma_bf16(qa[1], b1, r4);
#pragma unroll
        for (int j = 0; j < 4; ++j)
            Rel[(g * 4 + j) * 528 + rs * 16 + l15] = f2bf(r4[j]);
    }
    __syncthreads();

    // ---- scores: 4 quarters of 256 k-rows staged in LDS ----
    f32x4 acc[16];
#pragma unroll
    for (int i = 0; i < 16; ++i) acc[i] = (f32x4){0.f, 0.f, 0.f, 0.f};

    const int sgl8 = (lane & 7) ^ ((lane >> 3) & 7);   // staging logical granule
#pragma unroll
    for (int qtr = 0; qtr < 4; ++qtr) {
#pragma unroll
        for (int c = 0; c < 8; ++c) {
            int rbase = w * 64 + c * 8;
            async16(Kp + (size_t)(b * 1024 + qtr * 256 + rbase + (lane >> 3)) * kstride
                       + h * 64 + sgl8 * 8,
                    &Ks[rbase * 64]);
        }
        __syncthreads();
#pragma unroll
        for (int n = 0; n < 4; ++n) {
            int row = w * 64 + n * 16 + l15;
            short8v kb0 = *(const short8v*)&Ks[row * 64 + ((g ^ (row & 7))) * 8];
            short8v kb1 = *(const short8v*)&Ks[row * 64 + (((4 + g) ^ (row & 7))) * 8];
            acc[qtr * 4 + n] = mfma_bf16(qa[0], kb0, acc[qtr * 4 + n]);
            acc[qtr * 4 + n] = mfma_bf16(qa[1], kb1, acc[qtr * 4 + n]);
        }
        __syncthreads();
    }

    // ---- epilogue: + rel, * 1/8, + mask * -1e9 ----
    const int qb = q0 + g * 4;     // global q for j=0
    const int ql = g * 4;          // local q for j=0
    const float* mrow = mask + ((size_t)b * 1024 + qb) * 1024;
#pragma unroll
    for (int na = 0; na < 16; ++na) {
        int k = (na >> 2) * 256 + w * 64 + (na & 3) * 16 + l15;
#pragma unroll
        for (int j = 0; j < 4; ++j) {
            int q = qb + j;
            int d = k - q; d = d < -256 ? -256 : (d > 256 ? 256 : d);
            float rel = bf2f(Rel[(ql + j) * 528 + d + 256]);
            float mv = mrow[(size_t)j * 1024 + k];
            acc[na][j] = (acc[na][j] + rel) * 0.125f + mv * (-1e9f);
        }
    }

    // ---- row max ----
    float mx[4];
#pragma unroll
    for (int j = 0; j < 4; ++j) {
        float m = acc[0][j];
#pragma unroll
        for (int na = 1; na < 16; ++na) m = fmaxf(m, acc[na][j]);
#pragma unroll
        for (int off = 1; off < 16; off <<= 1) m = fmaxf(m, __shfl_xor(m, off));
        mx[j] = m;
    }
    if (l15 == 0) {
#pragma unroll
        for (int j = 0; j < 4; ++j) Red[0][w][ql + j] = mx[j];
    }
    __syncthreads();
#pragma unroll
    for (int j = 0; j < 4; ++j) {
        float m = Red[0][0][ql + j];
        m = fmaxf(m, Red[0][1][ql + j]);
        m = fmaxf(m, Red[0][2][ql + j]);
        m = fmaxf(m, Red[0][3][ql + j]);
        mx[j] = m;
    }

    // ---- exp + row sum ----
    float sm[4] = {0.f, 0.f, 0.f, 0.f};
#pragma unroll
    for (int na = 0; na < 16; ++na)
#pragma unroll
        for (int j = 0; j < 4; ++j) {
            float e = __expf(acc[na][j] - mx[j]);
            acc[na][j] = e;
            sm[j] += e;
        }
#pragma unroll
    for (int j = 0; j < 4; ++j)
#pragma unroll
        for (int off = 1; off < 16; off <<= 1) sm[j] += __shfl_xor(sm[j], off);
    if (l15 == 0) {
#pragma unroll
        for (int j = 0; j < 4; ++j) Red[1][w][ql + j] = sm[j];
    }
    __syncthreads();
#pragma unroll
    for (int j = 0; j < 4; ++j) {
        float s = Red[1][0][ql + j] + Red[1][1][ql + j]
                + Red[1][2][ql + j] + Red[1][3][ql + j];
        sm[j] = 1.0f / s;
    }
    // NOTE: Ks region is dead from here; Pl aliases it (sync above separates).

    // ---- normalize: write global weights + bf16 P into LDS ----
    float* wbase = Wout + ((size_t)bh * 1024 + qb) * 1024;
#pragma unroll
    for (int na = 0; na < 16; ++na) {
        int k = (na >> 2) * 256 + w * 64 + (na & 3) * 16 + l15;
#pragma unroll
        for (int j = 0; j < 4; ++j) {
            float p = acc[na][j] * sm[j];
            wbase[(size_t)j * 1024 + k] = p;
            Pl[((k >> 3) * 16 + (ql + j)) * 8 + (k & 7)] = f2bf(p);
        }
    }
    __syncthreads();

    // ---- PV: O[16 q][64 d] ; wave w owns d-tile [w*16, w*16+16) ----
    f32x4 oacc = (f32x4){0.f, 0.f, 0.f, 0.f};
    const int vgl = (lane & 15) ^ ((t >> 4) & 15);  // staging granule (row = idx*4 + l>>4)
#pragma unroll
    for (int c = 0; c < 8; ++c) {
        // stage Vs[64][128] from Vt, pre-swizzled source (16 slots/row)
        {
            int idx = w * 4;       // 4 calls per wave, rows idx*4..idx*4+3 each
#pragma unroll
            for (int i = 0; i < 4; ++i) {
                int d = (idx + i) * 4 + (lane >> 4);
                int gl = (lane & 15) ^ (d & 15);
                async16(Vt + ((size_t)bh * 64 + d) * 1024 + c * 128 + gl * 8,
                        &Vs[(idx + i) * 512]);
            }
        }
        __syncthreads();
#pragma unroll
        for (int ks = 0; ks < 4; ++ks) {
            int kg = c * 4 + ks;   // global 32-k step
            short8v a = *(const short8v*)&Pl[((kg * 4 + g) * 16 + l15) * 8];
            int rowv = w * 16 + l15;
            short8v bb = *(const short8v*)&Vs[rowv * 128 + (((ks * 4 + g) ^ (rowv & 15))) * 8];
            oacc = mfma_bf16(a, bb, oacc);
        }
        __syncthreads();
    }
#pragma unroll
    for (int j = 0; j < 4; ++j)
        Hout[(size_t)(b * 1024 + q0 + g * 4 + j) * 512 + h * 64 + w * 16 + l15]
            = f2bf(oacc[j]);
}

// ---------------------------------------------------------------------------
// V transpose per head: V[b,k,h*64+d] (bf16, given row stride) -> Vt[bh,d,k]
// Grid (8 k-tiles(128), 64 bh).
// ---------------------------------------------------------------------------
__global__ __launch_bounds__(256) void transpose_v(
    const unsigned short* __restrict__ Vb, int stride, unsigned short* __restrict__ Vt)
{
    __shared__ unsigned short T[128][72];
    const int bh = blockIdx.y, b = bh >> 3, h = bh & 7;
    const int k0 = blockIdx.x * 128;
    const int t = threadIdx.x;
    {
        int r = t >> 1, half = t & 1;
        const unsigned short* gp = Vb + (size_t)(b * 1024 + k0 + r) * stride + h * 64 + half * 32;
#pragma unroll
        for (int i = 0; i < 8; ++i)
            *(short4v*)&T[r][half * 32 + i * 4] = *(const short4v*)(gp + i * 4);
    }
    __syncthreads();
    {
        int d = t >> 2, qtr = t & 3;
        unsigned short* gp = Vt + ((size_t)bh * 64 + d) * 1024 + k0 + qtr * 32;
#pragma unroll
        for (int i = 0; i < 32; i += 4) {
            short4v v;
            v.x = T[qtr * 32 + i + 0][d];
            v.y = T[qtr * 32 + i + 1][d];
            v.z = T[qtr * 32 + i + 2][d];
            v.w = T[qtr * 32 + i + 3][d];
            *(short4v*)(gp + i) = v;
        }
    }
}

// ---------------------------------------------------------------------------
// LayerNorm over 512: out = LN(Xp + Res)*g + be (+ optional bf16 copy).
// ---------------------------------------------------------------------------
__global__ __launch_bounds__(128) void ln512(
    const float* __restrict__ Xp, const float* __restrict__ Res,
    const float* __restrict__ g, const float* __restrict__ be,
    float* __restrict__ out, unsigned short* __restrict__ outb)
{
    const size_t row = blockIdx.x;
    const int t = threadIdx.x;
    float4 x = *(const float4*)(Xp + row * 512 + t * 4);
    float4 r = *(const float4*)(Res + row * 512 + t * 4);
    x.x += r.x; x.y += r.y; x.z += r.z; x.w += r.w;
    float s  = x.x + x.y + x.z + x.w;
    float ss = x.x * x.x + x.y * x.y + x.z * x.z + x.w * x.w;
#pragma unroll
    for (int o = 32; o > 0; o >>= 1) { s += __shfl_xor(s, o); ss += __shfl_xor(ss, o); }
    __shared__ float sm[2], sq[2];
    if ((t & 63) == 0) { sm[t >> 6] = s; sq[t >> 6] = ss; }
    __syncthreads();
    s = sm[0] + sm[1]; ss = sq[0] + sq[1];
    const float mean = s * (1.f / 512.f);
    const float var  = ss * (1.f / 512.f) - mean * mean;
    const float rstd = rsqrtf(var + 1e-3f);
    float4 gv = *(const float4*)(g + t * 4), bv = *(const float4*)(be + t * 4);
    float4 o;
    o.x = (x.x - mean) * rstd * gv.x + bv.x;
    o.y = (x.y - mean) * rstd * gv.y + bv.y;
    o.z = (x.z - mean) * rstd * gv.z + bv.z;
    o.w = (x.w - mean) * rstd * gv.w + bv.w;
    *(float4*)(out + row * 512 + t * 4) = o;
    if (outb) {
        short4v q4;
        q4.x = f2bf(o.x); q4.y = f2bf(o.y); q4.z = f2bf(o.z); q4.w = f2bf(o.w);
        *(short4v*)(outb + row * 512 + t * 4) = q4;
    }
}

// ---------------------------------------------------------------------------
// Weight transpose-cast: W[K][N] fp32 -> WT[N][K] bf16. Grid (N/64, K/64).
// ---------------------------------------------------------------------------
__global__ __launch_bounds__(256) void wt_cast(
    const float* __restrict__ W, unsigned short* __restrict__ WT, int K, int N)
{
    __shared__ float T[64][68];
    const int t = threadIdx.x;
    const int k0 = blockIdx.y * 64, n0 = blockIdx.x * 64;
    int r = t >> 4, c = (t & 15) * 4;
#pragma unroll
    for (int p = 0; p < 4; ++p) {
        float4 v = *(const float4*)(W + (size_t)(k0 + r + p * 16) * N + n0 + c);
        T[r + p * 16][c + 0] = v.x; T[r + p * 16][c + 1] = v.y;
        T[r + p * 16][c + 2] = v.z; T[r + p * 16][c + 3] = v.w;
    }
    __syncthreads();
#pragma unroll
    for (int p = 0; p < 4; ++p) {
        int n = r + p * 16;
        short4v o;
        o.x = f2bf(T[c + 0][n]); o.y = f2bf(T[c + 1][n]);
        o.z = f2bf(T[c + 2][n]); o.w = f2bf(T[c + 3][n]);
        *(short4v*)(WT + (size_t)(n0 + n) * K + k0 + c) = o;
    }
}

__global__ __launch_bounds__(256) void cast_bf16(
    const float* __restrict__ in, unsigned short* __restrict__ o, int n4)
{
    int i = blockIdx.x * 256 + threadIdx.x;
    if (i < n4) {
        float4 v = *(const float4*)(in + (size_t)i * 4);
        short4v s;
        s.x = f2bf(v.x); s.y = f2bf(v.y); s.z = f2bf(v.z); s.w = f2bf(v.w);
        *(short4v*)(o + (size_t)i * 4) = s;
    }
}

// pack up to 3 512-long bias vectors into one contiguous fp32 buffer
__global__ __launch_bounds__(256) void pack_bias(
    float* __restrict__ o, const float* __restrict__ a,
    const float* __restrict__ b, const float* __restrict__ c, int n)
{
    int i = blockIdx.x * 256 + threadIdx.x;
    if (i >= n) return;
    float v;
    if (i < 512) v = a[i];
    else if (i < 1024) v = b[i - 512];
    else v = c[i - 1024];
    o[i] = v;
}

// ---------------------------------------------------------------------------

extern "C" void kernel_launch(void* const* d_in, const int* in_sizes, int n_in,
                              void* d_out, int out_size, void* d_ws, size_t ws_size,
                              hipStream_t stream)
{
    (void)in_sizes; (void)n_in; (void)out_size;
    const float* inputs    = (const float*)d_in[0];
    const float* enc_kv    = (const float*)d_in[1];
    const float* pad_mask  = (const float*)d_in[2];
    const float* look_mask = (const float*)d_in[3];
    const float* saWq  = (const float*)d_in[5];
    const float* sabq  = (const float*)d_in[6];
    const float* saWk  = (const float*)d_in[7];
    const float* sabk  = (const float*)d_in[8];
    const float* saWv  = (const float*)d_in[9];
    const float* sabv  = (const float*)d_in[10];
    const float* saWo  = (const float*)d_in[11];
    const float* sabo  = (const float*)d_in[12];
    const float* sarel = (const float*)d_in[13];
    const float* salg  = (const float*)d_in[14];
    const float* salb  = (const float*)d_in[15];
    const float* caWq  = (const float*)d_in[16];
    const float* cabq  = (const float*)d_in[17];
    const float* caWk  = (const float*)d_in[18];
    const float* cabk  = (const float*)d_in[19];
    const float* caWv  = (const float*)d_in[20];
    const float* cabv  = (const float*)d_in[21];
    const float* caWo  = (const float*)d_in[22];
    const float* cabo  = (const float*)d_in[23];
    const float* carel = (const float*)d_in[24];
    const float* calg  = (const float*)d_in[25];
    const float* calb  = (const float*)d_in[26];
    const float* fW1   = (const float*)d_in[27];
    const float* fb1   = (const float*)d_in[28];
    const float* fW2   = (const float*)d_in[29];
    const float* fb2   = (const float*)d_in[30];
    const float* flg   = (const float*)d_in[31];
    const float* flb   = (const float*)d_in[32];

    float* out    = (float*)d_out;
    float* attn_w = out + (size_t)8 * 1024 * 512;
    float* ca_w   = attn_w + (size_t)8 * 8 * 1024 * 1024;

    // ---- workspace layout ----
    char* ws = (char*)d_ws;
    size_t off = 0;
    unsigned short* WTa = (unsigned short*)(ws + off); off += 8519936;   // weights bf16
    float* bqkv = (float*)(ws + off); off += 8192;                       // packed sa q|k|v bias
    float* bkv  = (float*)(ws + off); off += 8192;                       // packed ca k|v bias
    unsigned short* Abf   = (unsigned short*)(ws + off); off += 8388608; // act bf16 [8192][512]
    unsigned short* x1bf  = (unsigned short*)(ws + off); off += 8388608;
    unsigned short* Qca   = (unsigned short*)(ws + off); off += 8388608;
    unsigned short* heads = (unsigned short*)(ws + off); off += 8388608;
    unsigned short* Vt    = (unsigned short*)(ws + off); off += 8388608; // [64][64][1024]
    unsigned short* KV    = (unsigned short*)(ws + off); off += 16777216;// [8192][1024]
    unsigned short* big   = (unsigned short*)(ws + off); off += 33554432;// QKV / FFN hidden
    float* x1 = (float*)(ws + off); off += 16777216;
    float* x2 = (float*)(ws + off); off += 16777216;
    float* Pb = (float*)(ws + off); off += 16777216;
    if (ws_size < off) {
        fprintf(stderr, "kernel_launch: ws too small (%zu < %zu)\n", ws_size, off);
        return;
    }
    unsigned short* QKV    = big;                 // [8192][1536] (SA only)
    unsigned short* hidden = big;                 // [8192][2048] (FFN only)
    unsigned short* x2bf   = Abf;                 // alias: enc bf16 dead by then

    // weight sub-buffers inside WTa (contiguity gives fused-QKV BT for free)
    unsigned short* saWqT = WTa + 0;              // rows 0-511   of [1536][512]
    unsigned short* saWkT = WTa + 262144;         // rows 512-1023
    unsigned short* saWvT = WTa + 524288;         // rows 1024-1535
    unsigned short* saWoT = WTa + 786432;
    unsigned short* caWqT = WTa + 1048576;
    unsigned short* caWkT = WTa + 1310720;        // rows 0-511   of [1024][512]
    unsigned short* caWvT = WTa + 1572864;        // rows 512-1023
    unsigned short* caWoT = WTa + 1835008;
    unsigned short* W1T   = WTa + 2097152;
    unsigned short* W2T   = WTa + 3145728;
    unsigned short* relSA = WTa + 4194304;
    unsigned short* relCA = WTa + 4227136;

    const dim3 T256(256), T128(128);

    // ---- prep ----
    wt_cast<<<dim3(8, 8),  T256, 0, stream>>>(saWq, saWqT, 512, 512);
    wt_cast<<<dim3(8, 8),  T256, 0, stream>>>(saWk, saWkT, 512, 512);
    wt_cast<<<dim3(8, 8),  T256, 0, stream>>>(saWv, saWvT, 512, 512);
    wt_cast<<<dim3(8, 8),  T256, 0, stream>>>(saWo, saWoT, 512, 512);
    wt_cast<<<dim3(8, 8),  T256, 0, stream>>>(caWq, caWqT, 512, 512);
    wt_cast<<<dim3(8, 8),  T256, 0, stream>>>(caWk, caWkT, 512, 512);
    wt_cast<<<dim3(8, 8),  T256, 0, stream>>>(caWv, caWvT, 512, 512);
    wt_cast<<<dim3(8, 8),  T256, 0, stream>>>(caWo, caWoT, 512, 512);
    wt_cast<<<dim3(32, 8), T256, 0, stream>>>(fW1, W1T, 512, 2048);
    wt_cast<<<dim3(8, 32), T256, 0, stream>>>(fW2, W2T, 2048, 512);
    cast_bf16<<<dim3(33),   T256, 0, stream>>>(sarel, relSA, 8208);
    cast_bf16<<<dim3(33),   T256, 0, stream>>>(carel, relCA, 8208);
    cast_bf16<<<dim3(4096), T256, 0, stream>>>(inputs, Abf, 1048576);
    pack_bias<<<dim3(6), T256, 0, stream>>>(bqkv, sabq, sabk, sabv, 1536);
    pack_bias<<<dim3(4), T256, 0, stream>>>(bkv, cabk, cabv, nullptr, 1024);

    // ---- self attention ----
    gemm_bf16<<<dim3(12, 64), T256, 0, stream>>>(Abf, saWqT, bqkv, nullptr, QKV, 8192, 1536, 512, 0);
    transpose_v<<<dim3(8, 64), T256, 0, stream>>>(QKV + 1024, 1536, Vt);
    fused_attn<<<dim3(64, 64), T256, 0, stream>>>(QKV, 1536, QKV + 512, 1536, Vt, relSA, look_mask, attn_w, heads);
    gemm_bf16<<<dim3(4, 64), T256, 0, stream>>>(heads, saWoT, sabo, Pb, nullptr, 8192, 512, 512, 0);
    ln512<<<dim3(8192), T128, 0, stream>>>(Pb, inputs, salg, salb, x1, x1bf);

    // ---- cross attention ----
    cast_bf16<<<dim3(4096), T256, 0, stream>>>(enc_kv, Abf, 1048576);
    gemm_bf16<<<dim3(8, 64), T256, 0, stream>>>(Abf, caWkT, bkv, nullptr, KV, 8192, 1024, 512, 0);
    gemm_bf16<<<dim3(4, 64), T256, 0, stream>>>(x1bf, caWqT, cabq, nullptr, Qca, 8192, 512, 512, 0);
    transpose_v<<<dim3(8, 64), T256, 0, stream>>>(KV + 512, 1024, Vt);
    fused_attn<<<dim3(64, 64), T256, 0, stream>>>(Qca, 512, KV, 1024, Vt, relCA, pad_mask, ca_w, heads);
    gemm_bf16<<<dim3(4, 64), T256, 0, stream>>>(heads, caWoT, cabo, Pb, nullptr, 8192, 512, 512, 0);
    ln512<<<dim3(8192), T128, 0, stream>>>(Pb, x1, calg, calb, x2, x2bf);

    // ---- FFN ----
    gemm_bf16<<<dim3(16, 64), T256, 0, stream>>>(x2bf, W1T, fb1, nullptr, hidden, 8192, 2048, 512, 1);
    gemm_bf16<<<dim3(4, 64), T256, 0, stream>>>(hidden, W2T, fb2, Pb, nullptr, 8192, 512, 2048, 0);
    ln512<<<dim3(8192), T128, 0, stream>>>(Pb, x2, flg, flb, out, nullptr);
}

// Round 5
// 598.605 us; speedup vs baseline: 3.2235x; 1.0992x over previous
//
#include <hip/hip_runtime.h>
#include <hip/hip_bf16.h>
#include <cstdio>

// ---------------------------------------------------------------------------
// Decoder layer: B=8, L=1024, D=512, H=8, depth=64, FFN=2048, MAX_REL=256
// Outputs (fp32, concat): out[8,1024,512], attn_w[8,8,1024,1024], ca_w[same]
// Round 4: split-K for the 256-block GEMMs (occupancy), CA dual-GEMM merge,
//          prep-phase kernel merging (15 -> 5 dispatches).
// ---------------------------------------------------------------------------

typedef __attribute__((ext_vector_type(8))) short short8v;   // 8 bf16 (4 VGPR)
typedef __attribute__((ext_vector_type(4))) short short4v;   // 4 bf16 (8 B)
typedef __attribute__((ext_vector_type(4))) float f32x4;

static __device__ __forceinline__ unsigned short f2bf(float f) {
    unsigned int u = __float_as_uint(f);
    unsigned int r = (u + 0x7fffu + ((u >> 16) & 1u)) >> 16;
    return (unsigned short)r;
}
static __device__ __forceinline__ float bf2f(unsigned short s) {
    return __uint_as_float(((unsigned int)s) << 16);
}

static __device__ __forceinline__ f32x4 mfma_bf16(short8v a, short8v b, f32x4 c) {
    return __builtin_amdgcn_mfma_f32_16x16x32_bf16(a, b, c, 0, 0, 0);
}

// async global->LDS, 16B per lane. LDS dest: wave-uniform base + lane*16.
static __device__ __forceinline__ void async16(const void* g, void* l) {
    __builtin_amdgcn_global_load_lds(
        (const __attribute__((address_space(1))) unsigned int*)g,
        (__attribute__((address_space(3))) unsigned int*)l,
        16, 0, 0);
}

// Fragment conventions for mfma_f32_16x16x32_bf16 (verified rounds 1-3):
//   A-frag: lane holds A[row = lane&15][k = (lane>>4)*8 + j]
//   B-frag: lane holds B[k = (lane>>4)*8 + j][col = lane&15]
//   C/D   : col = lane&15, row = (lane>>4)*4 + reg
// LDS rows = 16-B slots; stored slot = logical ^ swizzle(row), applied on the
// pre-swizzled global source of global_load_lds AND on the ds_read side.

// ---------------------------------------------------------------------------
// Core bf16 MFMA GEMM tile: C[128,128] at (m0,n0) = A[M,K] @ BT[N,K]^T + bias
// 256 threads (4 waves, 2x2). Kblk = K-range this block accumulates.
// ---------------------------------------------------------------------------
static __device__ __forceinline__ void gemm_core(
    unsigned short* As, unsigned short* Bs,
    const unsigned short* __restrict__ A, int lda,
    const unsigned short* __restrict__ BT, int ldb,
    const float* __restrict__ bias, float* __restrict__ Cf,
    unsigned short* __restrict__ Cb, int ldc,
    int m0, int n0, int Kblk, int relu)
{
    const int t = threadIdx.x, lane = t & 63, w = t >> 6;
    const int wm = w >> 1, wn = w & 1;
    f32x4 acc[4][4];
#pragma unroll
    for (int m = 0; m < 4; ++m)
#pragma unroll
        for (int n = 0; n < 4; ++n) acc[m][n] = (f32x4){0.f, 0.f, 0.f, 0.f};

    const int srow = lane >> 2;
    const int sgl  = (lane & 3) ^ ((lane >> 3) & 3);   // pre-swizzled k-granule
    for (int k0 = 0; k0 < Kblk; k0 += 32) {
#pragma unroll
        for (int c = w; c < 8; c += 4) {
            async16(A  + (size_t)(m0 + c * 16 + srow) * lda + k0 + sgl * 8, &As[c * 512]);
            async16(BT + (size_t)(n0 + c * 16 + srow) * ldb + k0 + sgl * 8, &Bs[c * 512]);
        }
        __syncthreads();
        short8v a[4], b[4];
        const int g = lane >> 4, l15 = lane & 15;
        const int ss = (g ^ ((l15 >> 1) & 3)) * 8;
#pragma unroll
        for (int m = 0; m < 4; ++m)
            a[m] = *(const short8v*)&As[(wm * 64 + m * 16 + l15) * 32 + ss];
#pragma unroll
        for (int n = 0; n < 4; ++n)
            b[n] = *(const short8v*)&Bs[(wn * 64 + n * 16 + l15) * 32 + ss];
#pragma unroll
        for (int m = 0; m < 4; ++m)
#pragma unroll
            for (int n = 0; n < 4; ++n)
                acc[m][n] = mfma_bf16(a[m], b[n], acc[m][n]);
        __syncthreads();
    }
#pragma unroll
    for (int m = 0; m < 4; ++m) {
        int gm = m0 + wm * 64 + m * 16 + (lane >> 4) * 4;
#pragma unroll
        for (int n = 0; n < 4; ++n) {
            int gn = n0 + wn * 64 + n * 16 + (lane & 15);
            float bv = bias ? bias[gn] : 0.f;
#pragma unroll
            for (int j = 0; j < 4; ++j) {
                float v = acc[m][n][j] + bv;
                if (relu) v = fmaxf(v, 0.f);
                size_t off = (size_t)(gm + j) * ldc + gn;
                if (Cf) Cf[off] = v;
                if (Cb) Cb[off] = f2bf(v);
            }
        }
    }
}

// Standard GEMM with optional split-K via blockIdx.z (partials stacked in Cf).
__global__ __launch_bounds__(256) void gemm_std(
    const unsigned short* __restrict__ A, int lda,
    const unsigned short* __restrict__ BT, int ldb,
    const float* __restrict__ bias,
    float* __restrict__ Cf, unsigned short* __restrict__ Cb,
    int N, int Kblk, int relu)
{
    __shared__ __attribute__((aligned(16))) unsigned short As[128 * 32];
    __shared__ __attribute__((aligned(16))) unsigned short Bs[128 * 32];
    const int kz = blockIdx.z;
    const size_t part = (size_t)kz * gridDim.y * 128 * N;
    gemm_core(As, Bs, A + kz * Kblk, lda, BT + kz * Kblk, ldb,
              kz == 0 ? bias : nullptr,
              Cf ? Cf + part : nullptr, Cb, N,
              blockIdx.y * 128, blockIdx.x * 128, Kblk, relu);
}

// CA dual projection: blocks 0..7 -> enc_kv @ Wkv (N=1024), 8..11 -> x1 @ Wq.
__global__ __launch_bounds__(256) void gemm_ca(
    const unsigned short* __restrict__ Ekv, const unsigned short* __restrict__ Xq,
    const unsigned short* __restrict__ WkvT, const unsigned short* __restrict__ WqT,
    const float* __restrict__ bkv, const float* __restrict__ bq,
    unsigned short* __restrict__ KV, unsigned short* __restrict__ Q)
{
    __shared__ __attribute__((aligned(16))) unsigned short As[128 * 32];
    __shared__ __attribute__((aligned(16))) unsigned short Bs[128 * 32];
    const int bx = blockIdx.x;
    if (bx < 8)
        gemm_core(As, Bs, Ekv, 512, WkvT, 512, bkv, nullptr, KV, 1024,
                  blockIdx.y * 128, bx * 128, 512, 0);
    else
        gemm_core(As, Bs, Xq, 512, WqT, 512, bq, nullptr, Q, 512,
                  blockIdx.y * 128, (bx - 8) * 128, 512, 0);
}

// ---------------------------------------------------------------------------
// Fused scores + softmax + PV (unchanged from round 3).
// ---------------------------------------------------------------------------
__global__ __launch_bounds__(256) void fused_attn(
    const unsigned short* __restrict__ Qp, int qstride,
    const unsigned short* __restrict__ Kp, int kstride,
    const unsigned short* __restrict__ Vt,     // [bh][64][1024] bf16
    const unsigned short* __restrict__ relW,   // [513][64] bf16
    const float* __restrict__ mask,            // [8][1024][1024] fp32
    float* __restrict__ Wout,                  // [64][1024][1024] fp32
    unsigned short* __restrict__ Hout)         // [8192][512] bf16
{
    __shared__ __attribute__((aligned(16))) unsigned short Qs[16 * 64];
    __shared__ __attribute__((aligned(16))) unsigned short Rel[16 * 528];
    __shared__ __attribute__((aligned(16))) unsigned short U[24576];  // 48 KB
    __shared__ float Red[2][4][16];
    unsigned short* Ks = U;              // [256][64] during scores
    unsigned short* Pl = U;              // [128 kg][16 q][8] after scores
    unsigned short* Vs = U + 16384;      // [64 d][128 k] (swizzled slots)
    const int t = threadIdx.x, lane = t & 63, w = t >> 6;
    const int g = lane >> 4, l15 = lane & 15;
    const int bh = blockIdx.y, b = bh >> 3, h = bh & 7;
    const int q0 = blockIdx.x * 16;

    if (w < 2) {
        int row = w * 8 + (lane >> 3);
        int gl = (lane & 7) ^ ((lane >> 3) & 7);
        async16(Qp + (size_t)(b * 1024 + q0 + row) * qstride + h * 64 + gl * 8,
                &Qs[w * 512]);
    }
    __syncthreads();

    short8v qa[2];
#pragma unroll
    for (int kk = 0; kk < 2; ++kk)
        qa[kk] = *(const short8v*)&Qs[l15 * 64 + (((kk * 4 + g) ^ (l15 & 7))) * 8];

    for (int rs = w; rs < 33; rs += 4) {
        int rc = rs * 16 + l15;
        int re = rc > 512 ? 512 : rc;
        short8v b0 = *(const short8v*)(relW + (size_t)re * 64 + g * 8);
        short8v b1 = *(const short8v*)(relW + (size_t)re * 64 + 32 + g * 8);
        f32x4 r4 = (f32x4){0.f, 0.f, 0.f, 0.f};
        r4 = mfma_bf16(qa[0], b0, r4);
        r4 = mfma_bf16(qa[1], b1, r4);
#pragma unroll
        for (int j = 0; j < 4; ++j)
            Rel[(g * 4 + j) * 528 + rs * 16 + l15] = f2bf(r4[j]);
    }
    __syncthreads();

    f32x4 acc[16];
#pragma unroll
    for (int i = 0; i < 16; ++i) acc[i] = (f32x4){0.f, 0.f, 0.f, 0.f};

    const int sgl8 = (lane & 7) ^ ((lane >> 3) & 7);
#pragma unroll
    for (int qtr = 0; qtr < 4; ++qtr) {
#pragma unroll
        for (int c = 0; c < 8; ++c) {
            int rbase = w * 64 + c * 8;
            async16(Kp + (size_t)(b * 1024 + qtr * 256 + rbase + (lane >> 3)) * kstride
                       + h * 64 + sgl8 * 8,
                    &Ks[rbase * 64]);
        }
        __syncthreads();
#pragma unroll
        for (int n = 0; n < 4; ++n) {
            int row = w * 64 + n * 16 + l15;
            short8v kb0 = *(const short8v*)&Ks[row * 64 + ((g ^ (row & 7))) * 8];
            short8v kb1 = *(const short8v*)&Ks[row * 64 + (((4 + g) ^ (row & 7))) * 8];
            acc[qtr * 4 + n] = mfma_bf16(qa[0], kb0, acc[qtr * 4 + n]);
            acc[qtr * 4 + n] = mfma_bf16(qa[1], kb1, acc[qtr * 4 + n]);
        }
        __syncthreads();
    }

    const int qb = q0 + g * 4;
    const int ql = g * 4;
    const float* mrow = mask + ((size_t)b * 1024 + qb) * 1024;
#pragma unroll
    for (int na = 0; na < 16; ++na) {
        int k = (na >> 2) * 256 + w * 64 + (na & 3) * 16 + l15;
#pragma unroll
        for (int j = 0; j < 4; ++j) {
            int q = qb + j;
            int d = k - q; d = d < -256 ? -256 : (d > 256 ? 256 : d);
            float rel = bf2f(Rel[(ql + j) * 528 + d + 256]);
            float mv = mrow[(size_t)j * 1024 + k];
            acc[na][j] = (acc[na][j] + rel) * 0.125f + mv * (-1e9f);
        }
    }

    float mx[4];
#pragma unroll
    for (int j = 0; j < 4; ++j) {
        float m = acc[0][j];
#pragma unroll
        for (int na = 1; na < 16; ++na) m = fmaxf(m, acc[na][j]);
#pragma unroll
        for (int off = 1; off < 16; off <<= 1) m = fmaxf(m, __shfl_xor(m, off));
        mx[j] = m;
    }
    if (l15 == 0) {
#pragma unroll
        for (int j = 0; j < 4; ++j) Red[0][w][ql + j] = mx[j];
    }
    __syncthreads();
#pragma unroll
    for (int j = 0; j < 4; ++j) {
        float m = Red[0][0][ql + j];
        m = fmaxf(m, Red[0][1][ql + j]);
        m = fmaxf(m, Red[0][2][ql + j]);
        m = fmaxf(m, Red[0][3][ql + j]);
        mx[j] = m;
    }

    float sm[4] = {0.f, 0.f, 0.f, 0.f};
#pragma unroll
    for (int na = 0; na < 16; ++na)
#pragma unroll
        for (int j = 0; j < 4; ++j) {
            float e = __expf(acc[na][j] - mx[j]);
            acc[na][j] = e;
            sm[j] += e;
        }
#pragma unroll
    for (int j = 0; j < 4; ++j)
#pragma unroll
        for (int off = 1; off < 16; off <<= 1) sm[j] += __shfl_xor(sm[j], off);
    if (l15 == 0) {
#pragma unroll
        for (int j = 0; j < 4; ++j) Red[1][w][ql + j] = sm[j];
    }
    __syncthreads();
#pragma unroll
    for (int j = 0; j < 4; ++j) {
        float s = Red[1][0][ql + j] + Red[1][1][ql + j]
                + Red[1][2][ql + j] + Red[1][3][ql + j];
        sm[j] = 1.0f / s;
    }

    float* wbase = Wout + ((size_t)bh * 1024 + qb) * 1024;
#pragma unroll
    for (int na = 0; na < 16; ++na) {
        int k = (na >> 2) * 256 + w * 64 + (na & 3) * 16 + l15;
#pragma unroll
        for (int j = 0; j < 4; ++j) {
            float p = acc[na][j] * sm[j];
            wbase[(size_t)j * 1024 + k] = p;
            Pl[((k >> 3) * 16 + (ql + j)) * 8 + (k & 7)] = f2bf(p);
        }
    }
    __syncthreads();

    f32x4 oacc = (f32x4){0.f, 0.f, 0.f, 0.f};
#pragma unroll
    for (int c = 0; c < 8; ++c) {
        {
            int idx = w * 4;
#pragma unroll
            for (int i = 0; i < 4; ++i) {
                int d = (idx + i) * 4 + (lane >> 4);
                int gl = (lane & 15) ^ (d & 15);
                async16(Vt + ((size_t)bh * 64 + d) * 1024 + c * 128 + gl * 8,
                        &Vs[(idx + i) * 512]);
            }
        }
        __syncthreads();
#pragma unroll
        for (int ks = 0; ks < 4; ++ks) {
            int kg = c * 4 + ks;
            short8v a = *(const short8v*)&Pl[((kg * 4 + g) * 16 + l15) * 8];
            int rowv = w * 16 + l15;
            short8v bb = *(const short8v*)&Vs[rowv * 128 + (((ks * 4 + g) ^ (rowv & 15))) * 8];
            oacc = mfma_bf16(a, bb, oacc);
        }
        __syncthreads();
    }
#pragma unroll
    for (int j = 0; j < 4; ++j)
        Hout[(size_t)(b * 1024 + q0 + g * 4 + j) * 512 + h * 64 + w * 16 + l15]
            = f2bf(oacc[j]);
}

// ---------------------------------------------------------------------------
// V transpose per head: V[b,k,h*64+d] (bf16, stride) -> Vt[bh,d,k]
// ---------------------------------------------------------------------------
__global__ __launch_bounds__(256) void transpose_v(
    const unsigned short* __restrict__ Vb, int stride, unsigned short* __restrict__ Vt)
{
    __shared__ unsigned short T[128][72];
    const int bh = blockIdx.y, b = bh >> 3, h = bh & 7;
    const int k0 = blockIdx.x * 128;
    const int t = threadIdx.x;
    {
        int r = t >> 1, half = t & 1;
        const unsigned short* gp = Vb + (size_t)(b * 1024 + k0 + r) * stride + h * 64 + half * 32;
#pragma unroll
        for (int i = 0; i < 8; ++i)
            *(short4v*)&T[r][half * 32 + i * 4] = *(const short4v*)(gp + i * 4);
    }
    __syncthreads();
    {
        int d = t >> 2, qtr = t & 3;
        unsigned short* gp = Vt + ((size_t)bh * 64 + d) * 1024 + k0 + qtr * 32;
#pragma unroll
        for (int i = 0; i < 32; i += 4) {
            short4v v;
            v.x = T[qtr * 32 + i + 0][d];
            v.y = T[qtr * 32 + i + 1][d];
            v.z = T[qtr * 32 + i + 2][d];
            v.w = T[qtr * 32 + i + 3][d];
            *(short4v*)(gp + i) = v;
        }
    }
}

// ---------------------------------------------------------------------------
// LayerNorm over 512: out = LN(Xp0 [+ Xp1] + Res)*g + be (+ optional bf16).
// ---------------------------------------------------------------------------
__global__ __launch_bounds__(128) void ln512(
    const float* __restrict__ Xp0, const float* __restrict__ Xp1,
    const float* __restrict__ Res,
    const float* __restrict__ g, const float* __restrict__ be,
    float* __restrict__ out, unsigned short* __restrict__ outb)
{
    const size_t row = blockIdx.x;
    const int t = threadIdx.x;
    float4 x = *(const float4*)(Xp0 + row * 512 + t * 4);
    float4 r = *(const float4*)(Res + row * 512 + t * 4);
    x.x += r.x; x.y += r.y; x.z += r.z; x.w += r.w;
    if (Xp1) {
        float4 p = *(const float4*)(Xp1 + row * 512 + t * 4);
        x.x += p.x; x.y += p.y; x.z += p.z; x.w += p.w;
    }
    float s  = x.x + x.y + x.z + x.w;
    float ss = x.x * x.x + x.y * x.y + x.z * x.z + x.w * x.w;
#pragma unroll
    for (int o = 32; o > 0; o >>= 1) { s += __shfl_xor(s, o); ss += __shfl_xor(ss, o); }
    __shared__ float sm[2], sq[2];
    if ((t & 63) == 0) { sm[t >> 6] = s; sq[t >> 6] = ss; }
    __syncthreads();
    s = sm[0] + sm[1]; ss = sq[0] + sq[1];
    const float mean = s * (1.f / 512.f);
    const float var  = ss * (1.f / 512.f) - mean * mean;
    const float rstd = rsqrtf(var + 1e-3f);
    float4 gv = *(const float4*)(g + t * 4), bv = *(const float4*)(be + t * 4);
    float4 o;
    o.x = (x.x - mean) * rstd * gv.x + bv.x;
    o.y = (x.y - mean) * rstd * gv.y + bv.y;
    o.z = (x.z - mean) * rstd * gv.z + bv.z;
    o.w = (x.w - mean) * rstd * gv.w + bv.w;
    *(float4*)(out + row * 512 + t * 4) = o;
    if (outb) {
        short4v q4;
        q4.x = f2bf(o.x); q4.y = f2bf(o.y); q4.z = f2bf(o.z); q4.w = f2bf(o.w);
        *(short4v*)(outb + row * 512 + t * 4) = q4;
    }
}

// ---------------------------------------------------------------------------
// Weight transpose-cast: W[K][N] fp32 -> WT[N][K] bf16.
// ---------------------------------------------------------------------------
static __device__ __forceinline__ void wt_tile(
    const float* __restrict__ W, unsigned short* __restrict__ WT,
    int K, int N, int k0, int n0)
{
    __shared__ float T[64][68];
    const int t = threadIdx.x;
    int r = t >> 4, c = (t & 15) * 4;
#pragma unroll
    for (int p = 0; p < 4; ++p) {
        float4 v = *(const float4*)(W + (size_t)(k0 + r + p * 16) * N + n0 + c);
        T[r + p * 16][c + 0] = v.x; T[r + p * 16][c + 1] = v.y;
        T[r + p * 16][c + 2] = v.z; T[r + p * 16][c + 3] = v.w;
    }
    __syncthreads();
#pragma unroll
    for (int p = 0; p < 4; ++p) {
        int n = r + p * 16;
        short4v o;
        o.x = f2bf(T[c + 0][n]); o.y = f2bf(T[c + 1][n]);
        o.z = f2bf(T[c + 2][n]); o.w = f2bf(T[c + 3][n]);
        *(short4v*)(WT + (size_t)(n0 + n) * K + k0 + c) = o;
    }
}

__global__ __launch_bounds__(256) void wt_cast(
    const float* __restrict__ W, unsigned short* __restrict__ WT, int K, int N)
{
    wt_tile(W, WT, K, N, blockIdx.y * 64, blockIdx.x * 64);
}

struct Ptr8 {
    const float* s[8];
    unsigned short* d[8];
};

// 8 512x512 weight transposes in one launch: grid (8, 8, 8).
__global__ __launch_bounds__(256) void wt_cast8(Ptr8 p)
{
    wt_tile(p.s[blockIdx.z], p.d[blockIdx.z], 512, 512,
            blockIdx.y * 64, blockIdx.x * 64);
}

// rel-emb casts + bias packs in one launch (grid 68).
__global__ __launch_bounds__(256) void misc_prep(
    const float* __restrict__ sarel, const float* __restrict__ carel,
    unsigned short* __restrict__ relSA, unsigned short* __restrict__ relCA,
    const float* __restrict__ sabq, const float* __restrict__ sabk,
    const float* __restrict__ sabv, float* __restrict__ bqkv,
    const float* __restrict__ cabk, const float* __restrict__ cabv,
    float* __restrict__ bkv)
{
    const int bid = blockIdx.x, t = threadIdx.x;
    if (bid < 33) {
        int i = bid * 256 + t;
        if (i < 8208) {
            float4 v = *(const float4*)(sarel + (size_t)i * 4);
            short4v s;
            s.x = f2bf(v.x); s.y = f2bf(v.y); s.z = f2bf(v.z); s.w = f2bf(v.w);
            *(short4v*)(relSA + (size_t)i * 4) = s;
        }
    } else if (bid < 66) {
        int i = (bid - 33) * 256 + t;
        if (i < 8208) {
            float4 v = *(const float4*)(carel + (size_t)i * 4);
            short4v s;
            s.x = f2bf(v.x); s.y = f2bf(v.y); s.z = f2bf(v.z); s.w = f2bf(v.w);
            *(short4v*)(relCA + (size_t)i * 4) = s;
        }
    } else if (bid == 66) {
        for (int i = t; i < 1536; i += 256)
            bqkv[i] = i < 512 ? sabq[i] : (i < 1024 ? sabk[i - 512] : sabv[i - 1024]);
    } else {
        for (int i = t; i < 1024; i += 256)
            bkv[i] = i < 512 ? cabk[i] : cabv[i - 512];
    }
}

// dual fp32->bf16 cast: inputs and enc_kv in one launch (grid 8192).
__global__ __launch_bounds__(256) void cast2(
    const float* __restrict__ a, unsigned short* __restrict__ oa,
    const float* __restrict__ b, unsigned short* __restrict__ ob)
{
    size_t i = (size_t)blockIdx.x * 256 + threadIdx.x;
    const float* src; unsigned short* dst;
    if (i < 1048576) { src = a; dst = oa; }
    else { src = b; dst = ob; i -= 1048576; }
    float4 v = *(const float4*)(src + i * 4);
    short4v s;
    s.x = f2bf(v.x); s.y = f2bf(v.y); s.z = f2bf(v.z); s.w = f2bf(v.w);
    *(short4v*)(dst + i * 4) = s;
}

// ---------------------------------------------------------------------------

extern "C" void kernel_launch(void* const* d_in, const int* in_sizes, int n_in,
                              void* d_out, int out_size, void* d_ws, size_t ws_size,
                              hipStream_t stream)
{
    (void)in_sizes; (void)n_in; (void)out_size;
    const float* inputs    = (const float*)d_in[0];
    const float* enc_kv    = (const float*)d_in[1];
    const float* pad_mask  = (const float*)d_in[2];
    const float* look_mask = (const float*)d_in[3];
    const float* saWq  = (const float*)d_in[5];
    const float* sabq  = (const float*)d_in[6];
    const float* saWk  = (const float*)d_in[7];
    const float* sabk  = (const float*)d_in[8];
    const float* saWv  = (const float*)d_in[9];
    const float* sabv  = (const float*)d_in[10];
    const float* saWo  = (const float*)d_in[11];
    const float* sabo  = (const float*)d_in[12];
    const float* sarel = (const float*)d_in[13];
    const float* salg  = (const float*)d_in[14];
    const float* salb  = (const float*)d_in[15];
    const float* caWq  = (const float*)d_in[16];
    const float* cabq  = (const float*)d_in[17];
    const float* caWk  = (const float*)d_in[18];
    const float* cabk  = (const float*)d_in[19];
    const float* caWv  = (const float*)d_in[20];
    const float* cabv  = (const float*)d_in[21];
    const float* caWo  = (const float*)d_in[22];
    const float* cabo  = (const float*)d_in[23];
    const float* carel = (const float*)d_in[24];
    const float* calg  = (const float*)d_in[25];
    const float* calb  = (const float*)d_in[26];
    const float* fW1   = (const float*)d_in[27];
    const float* fb1   = (const float*)d_in[28];
    const float* fW2   = (const float*)d_in[29];
    const float* fb2   = (const float*)d_in[30];
    const float* flg   = (const float*)d_in[31];
    const float* flb   = (const float*)d_in[32];

    float* out    = (float*)d_out;
    float* attn_w = out + (size_t)8 * 1024 * 512;
    float* ca_w   = attn_w + (size_t)8 * 8 * 1024 * 1024;

    // ---- workspace layout ----
    char* ws = (char*)d_ws;
    size_t off = 0;
    unsigned short* WTa = (unsigned short*)(ws + off); off += 8519936;   // weights bf16
    float* bqkv = (float*)(ws + off); off += 8192;
    float* bkv  = (float*)(ws + off); off += 8192;
    unsigned short* Abf   = (unsigned short*)(ws + off); off += 8388608; // inputs bf16
    unsigned short* Ebf   = (unsigned short*)(ws + off); off += 8388608; // enc bf16
    unsigned short* x1bf  = (unsigned short*)(ws + off); off += 8388608;
    unsigned short* Qca   = (unsigned short*)(ws + off); off += 8388608;
    unsigned short* heads = (unsigned short*)(ws + off); off += 8388608;
    unsigned short* Vt    = (unsigned short*)(ws + off); off += 8388608; // [64][64][1024]
    unsigned short* KV    = (unsigned short*)(ws + off); off += 16777216;// [8192][1024]
    unsigned short* big   = (unsigned short*)(ws + off); off += 33554432;// QKV / FFN hidden
    float* x1 = (float*)(ws + off); off += 16777216;
    float* x2 = (float*)(ws + off); off += 16777216;
    float* Pb = (float*)(ws + off); off += 33554432;                     // 2 split-K partials
    if (ws_size < off) {
        fprintf(stderr, "kernel_launch: ws too small (%zu < %zu)\n", ws_size, off);
        return;
    }
    float* Pb1 = Pb + 4194304;                    // partial 1 (8192*512)
    unsigned short* QKV    = big;                 // [8192][1536] (SA only)
    unsigned short* hidden = big;                 // [8192][2048] (FFN only)
    unsigned short* x2bf   = Abf;                 // alias: inputs bf16 dead by then

    unsigned short* saWqT = WTa + 0;              // rows 0-511 of [1536][512]
    unsigned short* saWkT = WTa + 262144;
    unsigned short* saWvT = WTa + 524288;
    unsigned short* saWoT = WTa + 786432;
    unsigned short* caWqT = WTa + 1048576;
    unsigned short* caWkT = WTa + 1310720;        // rows 0-511 of [1024][512]
    unsigned short* caWvT = WTa + 1572864;
    unsigned short* caWoT = WTa + 1835008;
    unsigned short* W1T   = WTa + 2097152;
    unsigned short* W2T   = WTa + 3145728;
    unsigned short* relSA = WTa + 4194304;
    unsigned short* relCA = WTa + 4227136;

    const dim3 T256(256), T128(128);

    // ---- prep (5 dispatches) ----
    Ptr8 p8;
    p8.s[0] = saWq; p8.d[0] = saWqT;
    p8.s[1] = saWk; p8.d[1] = saWkT;
    p8.s[2] = saWv; p8.d[2] = saWvT;
    p8.s[3] = saWo; p8.d[3] = saWoT;
    p8.s[4] = caWq; p8.d[4] = caWqT;
    p8.s[5] = caWk; p8.d[5] = caWkT;
    p8.s[6] = caWv; p8.d[6] = caWvT;
    p8.s[7] = caWo; p8.d[7] = caWoT;
    wt_cast8<<<dim3(8, 8, 8), T256, 0, stream>>>(p8);
    wt_cast<<<dim3(32, 8), T256, 0, stream>>>(fW1, W1T, 512, 2048);
    wt_cast<<<dim3(8, 32), T256, 0, stream>>>(fW2, W2T, 2048, 512);
    misc_prep<<<dim3(68), T256, 0, stream>>>(sarel, carel, relSA, relCA,
                                             sabq, sabk, sabv, bqkv, cabk, cabv, bkv);
    cast2<<<dim3(8192), T256, 0, stream>>>(inputs, Abf, enc_kv, Ebf);

    // ---- self attention ----
    gemm_std<<<dim3(12, 64, 1), T256, 0, stream>>>(Abf, 512, WTa, 512, bqkv,
                                                   nullptr, QKV, 1536, 512, 0);
    transpose_v<<<dim3(8, 64), T256, 0, stream>>>(QKV + 1024, 1536, Vt);
    fused_attn<<<dim3(64, 64), T256, 0, stream>>>(QKV, 1536, QKV + 512, 1536, Vt,
                                                  relSA, look_mask, attn_w, heads);
    gemm_std<<<dim3(4, 64, 2), T256, 0, stream>>>(heads, 512, saWoT, 512, sabo,
                                                  Pb, nullptr, 512, 256, 0);
    ln512<<<dim3(8192), T128, 0, stream>>>(Pb, Pb1, inputs, salg, salb, x1, x1bf);

    // ---- cross attention ----
    gemm_ca<<<dim3(12, 64), T256, 0, stream>>>(Ebf, x1bf, caWkT, caWqT,
                                               bkv, cabq, KV, Qca);
    transpose_v<<<dim3(8, 64), T256, 0, stream>>>(KV + 512, 1024, Vt);
    fused_attn<<<dim3(64, 64), T256, 0, stream>>>(Qca, 512, KV, 1024, Vt,
                                                  relCA, pad_mask, ca_w, heads);
    gemm_std<<<dim3(4, 64, 2), T256, 0, stream>>>(heads, 512, caWoT, 512, cabo,
                                                  Pb, nullptr, 512, 256, 0);
    ln512<<<dim3(8192), T128, 0, stream>>>(Pb, Pb1, x1, calg, calb, x2, x2bf);

    // ---- FFN ----
    gemm_std<<<dim3(16, 64, 1), T256, 0, stream>>>(x2bf, 512, W1T, 512, fb1,
                                                   nullptr, hidden, 2048, 512, 1);
    gemm_std<<<dim3(4, 64, 2), T256, 0, stream>>>(hidden, 2048, W2T, 2048, fb2,
                                                  Pb, nullptr, 512, 1024, 0);
    ln512<<<dim3(8192), T128, 0, stream>>>(Pb, Pb1, x2, flg, flb, out, nullptr);
}